// Round 4
// baseline (294.127 us; speedup 1.0000x reference)
//
#include <hip/hip_runtime.h>
#include <math.h>

#define BATCH 256
#define CIN   512
#define CP    256
#define HW    361
#define NOUT  6

typedef short bf16x8 __attribute__((ext_vector_type(8)));
typedef float f32x4  __attribute__((ext_vector_type(4)));

__device__ __forceinline__ short f2bf(float f) {
    unsigned u = __float_as_uint(f);
    u += 0x7fffu + ((u >> 16) & 1u);
    return (short)(u >> 16);
}
__device__ __forceinline__ float bf2f(short s) {
    return __uint_as_float(((unsigned)(unsigned short)s) << 16);
}
// fast mish: mish(x) = x*(w-1)/(w+1), w=(1+e^x)^2.  Guard x>30 -> x (w overflow).
__device__ __forceinline__ float mish_f(float v) {
    float u = __expf(v);
    float a = 1.f + u;
    float w = a * a;
    float r = v * (w - 1.f) * __builtin_amdgcn_rcpf(w + 1.f);
    return (v > 30.f) ? v : r;
}
__device__ __forceinline__ void gl_lds16(const void* g, void* l) {
    __builtin_amdgcn_global_load_lds(
        (const __attribute__((address_space(1))) void*)g,
        (__attribute__((address_space(3))) void*)l, 16, 0, 0);
}

// ---------------------------------------------------------------------------
// K0a: weights f32 -> bf16, tiled + pre-swizzled [m(4)][kb(16)][row(128)][slot(4)*16B]
// rows 0-255 = w1p, 256-511 = w1g. Dest slot s holds source chunk s ^ ((row>>1)&3).
// ---------------------------------------------------------------------------
__global__ __launch_bounds__(256) void k0_weights(
    const float* __restrict__ w1p, const float* __restrict__ w1g,
    short* __restrict__ wT)
{
    int t = threadIdx.x;
    int r = blockIdx.x * 4 + (t >> 6);     // 0..511
    int cs = t & 63;                       // chunk-in-row: 64 x 8c
    int g = cs >> 2, s = cs & 3;           // kb group, dest slot
    int sc = s ^ ((r >> 1) & 3);           // source chunk
    const float* src = (r < 256) ? (w1p + (size_t)r * CIN)
                                 : (w1g + (size_t)(r - 256) * CIN);
    int c = g * 32 + sc * 8;
    float f[8];
    *(float4*)(f)     = *(const float4*)(src + c);
    *(float4*)(f + 4) = *(const float4*)(src + c + 4);
    bf16x8 v;
    #pragma unroll
    for (int i = 0; i < 8; ++i) v[i] = f2bf(f[i]);
    int m = r >> 7, rloc = r & 127;
    *(bf16x8*)((char*)wT + ((size_t)(m * 16 + g) * 128 + rloc) * 64 + s * 16) = v;
}

// ---------------------------------------------------------------------------
// K0b: x f32 [b][c][hw] -> bf16 tiled + pre-swizzled [b*3+n][kb16][row128][slot4*16B]
// Direct (no LDS): thread reads 8 c-strided f32 (lanes hw-consecutive ->
// coalesced 256B/instr), converts, writes one swizzled 16B chunk.
// ---------------------------------------------------------------------------
__global__ __launch_bounds__(256) void k0_xpose(
    const float* __restrict__ x, short* __restrict__ xT)
{
    int n = blockIdx.x, b = blockIdx.y;
    int t = threadIdx.x;
    int hw0 = n * 128;
    int row = t & 127;
    int s2 = t >> 7;                 // 0..1
    int hwg = hw0 + row;
    bool v = hwg < HW;
    char* dstb = (char*)xT + (size_t)(b * 3 + n) * 131072;
    const float* xb = x + (size_t)b * CIN * HW + hwg;
    for (int kb = 0; kb < 16; ++kb) {
        #pragma unroll
        for (int sp = 0; sp < 2; ++sp) {
            int s = sp * 2 + s2;
            int sc = s ^ ((row >> 1) & 3);
            const float* src = xb + (size_t)(kb * 32 + sc * 8) * HW;
            bf16x8 o;
            #pragma unroll
            for (int i = 0; i < 8; ++i) {
                float f = v ? src[(size_t)i * HW] : 0.f;
                o[i] = f2bf(f);
            }
            *(bf16x8*)(dstb + kb * 8192 + row * 64 + s * 16) = o;
        }
    }
}

// ---------------------------------------------------------------------------
// K1: fused conv1p+conv1g bf16 MFMA GEMM.
// BK=64, double-buffered LDS (2 x 32KB total = 64KB -> 2 blocks/CU), counted
// vmcnt(8) prefetch depth 1, raw s_barrier, setprio around MFMA cluster.
// Grid 3072, XCD-bijective remap, m fastest (4 m-blocks share one xT tile).
// ---------------------------------------------------------------------------
#define STAGE(h, p)                                                        \
    do {                                                                   \
        const char* ga_ = Ab + (p) * 16384;                                \
        const char* gb_ = Bb + (p) * 16384;                                \
        char* al_ = (char*)(&As[(h)][0]) + wid * 4096;                     \
        char* bl_ = (char*)(&Bs[(h)][0]) + wid * 4096;                     \
        _Pragma("unroll")                                                  \
        for (int q_ = 0; q_ < 4; ++q_) {                                   \
            gl_lds16(ga_ + q_ * 1024, al_ + q_ * 1024);                    \
            gl_lds16(gb_ + q_ * 1024, bl_ + q_ * 1024);                    \
        }                                                                  \
    } while (0)

__global__ __launch_bounds__(256, 2) void k1_conv1(
    const short* __restrict__ wT, const short* __restrict__ xT,
    const float* __restrict__ mask, const float* __restrict__ beta_g,
    short* __restrict__ outp_pre, float* __restrict__ psum, float* __restrict__ pmax)
{
    int orig = blockIdx.x;
    int newid = (orig & 7) * 384 + (orig >> 3);   // 3072 = 8 * 384, bijective
    int m = newid & 3;
    int nb = newid >> 2;          // b*3 + n
    int n = nb % 3;
    int b = nb / 3;

    const int tid = threadIdx.x;
    const int lane = tid & 63, wid = tid >> 6;
    const int wm = wid >> 1, wn = wid & 1;
    const int lc = lane & 15, lg = lane >> 4;
    const int hw0 = n * 128;

    __shared__ __align__(16) short As[2][8192];   // 2 x 16KB
    __shared__ __align__(16) short Bs[2][8192];
    __shared__ float maskS[128], betaS[128];
    // epilogue scratch overlays As (dead after main loop)
    float* redS = (float*)(&As[0][0]);
    float* redM = redS + 256;

    if (tid < 128) {
        int hwg = hw0 + tid;
        maskS[tid] = (hwg < HW) ? mask[b * HW + hwg] : 0.f;
        betaS[tid] = (m >= 2) ? beta_g[(m - 2) * 128 + tid] : 0.f;
    }
    // drain so counted vmcnt below starts from 0 outstanding
    asm volatile("s_waitcnt vmcnt(0) lgkmcnt(0)" ::: "memory");
    __builtin_amdgcn_sched_barrier(0);

    const char* Ab = (const char*)wT + (size_t)m * 131072 + wid * 4096 + lane * 16;
    const char* Bb = (const char*)xT + (size_t)nb * 131072 + wid * 4096 + lane * 16;

    f32x4 acc[4][4];
    #pragma unroll
    for (int i = 0; i < 4; ++i)
        #pragma unroll
        for (int j = 0; j < 4; ++j)
            acc[i][j] = (f32x4){0.f, 0.f, 0.f, 0.f};

    STAGE(0, 0);
    STAGE(1, 1);
    asm volatile("s_waitcnt vmcnt(8)" ::: "memory");   // stage0's 8 done
    __builtin_amdgcn_sched_barrier(0);
    __builtin_amdgcn_s_barrier();

    #pragma unroll
    for (int p = 0; p < 8; ++p) {
        const int h = p & 1;
        const char* ab = (const char*)(&As[h][0]);
        const char* bb = (const char*)(&Bs[h][0]);
        __builtin_amdgcn_s_setprio(1);
        #pragma unroll
        for (int q = 0; q < 2; ++q) {
            bf16x8 aF[4], bF[4];
            #pragma unroll
            for (int mf = 0; mf < 4; ++mf) {
                int r = wm * 64 + mf * 16 + lc;
                aF[mf] = *(const bf16x8*)(ab + q * 8192 + r * 64 + ((lg ^ ((r >> 1) & 3)) * 16));
            }
            #pragma unroll
            for (int nf = 0; nf < 4; ++nf) {
                int r = wn * 64 + nf * 16 + lc;
                bF[nf] = *(const bf16x8*)(bb + q * 8192 + r * 64 + ((lg ^ ((r >> 1) & 3)) * 16));
            }
            #pragma unroll
            for (int mf = 0; mf < 4; ++mf)
                #pragma unroll
                for (int nf = 0; nf < 4; ++nf)
                    acc[mf][nf] = __builtin_amdgcn_mfma_f32_16x16x32_bf16(
                        aF[mf], bF[nf], acc[mf][nf], 0, 0, 0);
        }
        __builtin_amdgcn_s_setprio(0);
        __builtin_amdgcn_s_barrier();          // all waves done reading buf h
        if (p < 6) {
            STAGE(h, p + 2);
            asm volatile("s_waitcnt vmcnt(8)" ::: "memory");  // stage p+1 ready
            __builtin_amdgcn_sched_barrier(0);
            __builtin_amdgcn_s_barrier();
        } else if (p == 6) {
            asm volatile("s_waitcnt vmcnt(0)" ::: "memory");  // stage 7 ready
            __builtin_amdgcn_sched_barrier(0);
            __builtin_amdgcn_s_barrier();
        }
    }
    __syncthreads();   // As reuse as redS/redM below

    if (m < 2) {
        // p-branch: store pre-activation conv1p output (bf16)
        #pragma unroll
        for (int mf = 0; mf < 4; ++mf) {
            int ch = m * 128 + wm * 64 + mf * 16 + lg * 4;
            #pragma unroll
            for (int nf = 0; nf < 4; ++nf) {
                int hw = hw0 + wn * 64 + nf * 16 + lc;
                if (hw < HW) {
                    #pragma unroll
                    for (int j = 0; j < 4; ++j)
                        outp_pre[((size_t)(b * CP + ch + j)) * HW + hw] = f2bf(acc[mf][nf][j]);
                }
            }
        }
    } else {
        // g-branch: mish((acc+beta)*mask); per-channel sum & max partials
        #pragma unroll
        for (int mf = 0; mf < 4; ++mf) {
            #pragma unroll
            for (int j = 0; j < 4; ++j) {
                int rloc = wm * 64 + mf * 16 + lg * 4 + j;
                float beta = betaS[rloc];
                float s = 0.f, mx = -INFINITY;
                #pragma unroll
                for (int nf = 0; nf < 4; ++nf) {
                    int cl = wn * 64 + nf * 16 + lc;
                    int hw = hw0 + cl;
                    float mv = maskS[cl];
                    float val = mish_f((acc[mf][nf][j] + beta) * mv);
                    if (hw < HW) {
                        s += val * mv;
                        mx = fmaxf(mx, val + mv - 1.f);
                    }
                }
                #pragma unroll
                for (int off = 1; off < 16; off <<= 1) {
                    s += __shfl_xor(s, off, 64);
                    mx = fmaxf(mx, __shfl_xor(mx, off, 64));
                }
                if (lc == 0) { redS[rloc * 2 + wn] = s; redM[rloc * 2 + wn] = mx; }
            }
        }
        __syncthreads();
        if (tid < 128) {
            int ch = (m - 2) * 128 + tid;
            float s = redS[tid * 2] + redS[tid * 2 + 1];
            float mx = fmaxf(redM[tid * 2], redM[tid * 2 + 1]);
            psum[((size_t)(b * CP + ch)) * 3 + n] = s;
            pmax[((size_t)(b * CP + ch)) * 3 + n] = mx;
        }
    }
}

// ---------------------------------------------------------------------------
// K2: per-batch pooled vector + linear_g. Grid 256 blocks x 256 threads.
// ---------------------------------------------------------------------------
__global__ __launch_bounds__(256) void k2_pool_linear(
    const float* __restrict__ mask, const float* __restrict__ psum,
    const float* __restrict__ pmax, const float* __restrict__ lw,
    float* __restrict__ g_out)
{
    int b = blockIdx.x, t = threadIdx.x;
    __shared__ float pooled[768];
    __shared__ float msr[4];

    float s = 0.f;
    for (int i = t; i < HW; i += 256) s += mask[b * HW + i];
    #pragma unroll
    for (int off = 1; off < 64; off <<= 1) s += __shfl_xor(s, off, 64);
    if ((t & 63) == 0) msr[t >> 6] = s;
    __syncthreads();
    float msum = msr[0] + msr[1] + msr[2] + msr[3];

    {
        int c = t;
        const float* ps = psum + (size_t)(b * CP + c) * 3;
        const float* pm = pmax + (size_t)(b * CP + c) * 3;
        float s3 = ps[0] + ps[1] + ps[2];
        float m3 = fmaxf(fmaxf(pm[0], pm[1]), pm[2]);
        float mean = s3 / msum;
        float sq = (sqrtf(msum) - 14.f) * 0.1f;
        pooled[c] = mean; pooled[256 + c] = mean * sq; pooled[512 + c] = m3;
    }
    __syncthreads();
    {
        int o = t;
        const float* wrow = lw + (size_t)o * 768;
        float acc = 0.f;
        #pragma unroll 4
        for (int j = 0; j < 768; ++j) acc += pooled[j] * wrow[j];
        g_out[b * CP + o] = acc;
    }
}

// ---------------------------------------------------------------------------
// K3: final fused mish((outp_pre+g+beta2)*mask) -> conv2p -> mask bias.
// outp_pre is bf16. Grid (6 hw-tiles, 256 b) x 256 threads.
// ---------------------------------------------------------------------------
__global__ __launch_bounds__(256) void k3_final(
    const short* __restrict__ outp_pre, const float* __restrict__ mask,
    const float* __restrict__ g_out, const float* __restrict__ beta2,
    const float* __restrict__ w2, float* __restrict__ out)
{
    int ht = blockIdx.x, b = blockIdx.y;
    int t = threadIdx.x;
    __shared__ float w2S[NOUT * 256];
    __shared__ float gbS[256];
    __shared__ float part[NOUT][256];

    for (int i = t; i < NOUT * 256; i += 256) w2S[i] = w2[i];
    gbS[t] = g_out[b * CP + t] + beta2[t];
    __syncthreads();

    int hw = t & 63, cg = t >> 6;
    int hwg = ht * 64 + hw;
    bool valid = hwg < HW;
    float maskv = valid ? mask[b * HW + hwg] : 0.f;

    float acc[NOUT] = {0.f, 0.f, 0.f, 0.f, 0.f, 0.f};
    const short* src = outp_pre + ((size_t)(b * CP + cg * 64)) * HW + hwg;
    #pragma unroll 4
    for (int ci = 0; ci < 64; ++ci) {
        float v = valid ? bf2f(src[(size_t)ci * HW]) : 0.f;
        float mm = mish_f((v + gbS[cg * 64 + ci]) * maskv);
        #pragma unroll
        for (int o = 0; o < NOUT; ++o) acc[o] += mm * w2S[o * 256 + cg * 64 + ci];
    }
    #pragma unroll
    for (int o = 0; o < NOUT; ++o) part[o][t] = acc[o];
    __syncthreads();

    for (int idx = t; idx < NOUT * 64; idx += 256) {
        int o = idx >> 6, h2 = idx & 63;
        int hg = ht * 64 + h2;
        if (hg < HW) {
            float mv = mask[b * HW + hg];
            float sum = part[o][h2] + part[o][64 + h2] + part[o][128 + h2] + part[o][192 + h2];
            out[((size_t)(b * NOUT + o)) * HW + hg] = sum - (1.f - mv) * 5000.f;
        }
    }
}

extern "C" void kernel_launch(void* const* d_in, const int* in_sizes, int n_in,
                              void* d_out, int out_size, void* d_ws, size_t ws_size,
                              hipStream_t stream) {
    const float* x     = (const float*)d_in[0];
    const float* mask  = (const float*)d_in[1];
    const float* w1p   = (const float*)d_in[2];
    const float* w1g   = (const float*)d_in[3];
    const float* betag = (const float*)d_in[4];
    const float* lw    = (const float*)d_in[5];
    const float* beta2 = (const float*)d_in[6];
    const float* w2    = (const float*)d_in[7];
    float* out = (float*)d_out;

    char* ws = (char*)d_ws;
    short* outp_pre = (short*)(ws);                      // 256*256*361*2 = 47,316,992 B
    short* xT       = (short*)(ws + 47316992);           // 768*131072    = 100,663,296 B
    short* wT       = (short*)(ws + 147980288);          // 4*131072      =     524,288 B
    float* psum     = (float*)(ws + 148504576);          // 256*256*3*4   =     786,432 B
    float* pmax     = (float*)(ws + 149291008);          // 256*256*3*4   =     786,432 B
    float* g_out    = (float*)(ws + 150077440);          // 256*256*4     =     262,144 B

    hipLaunchKernelGGL(k0_weights, dim3(128), dim3(256), 0, stream, w1p, w1g, wT);
    hipLaunchKernelGGL(k0_xpose, dim3(3, BATCH), dim3(256), 0, stream, x, xT);
    hipLaunchKernelGGL(k1_conv1, dim3(3072), dim3(256), 0, stream,
                       wT, xT, mask, betag, outp_pre, psum, pmax);
    hipLaunchKernelGGL(k2_pool_linear, dim3(BATCH), dim3(256), 0, stream,
                       mask, psum, pmax, lw, g_out);
    hipLaunchKernelGGL(k3_final, dim3(6, BATCH), dim3(256), 0, stream,
                       outp_pre, mask, g_out, beta2, w2, out);
    (void)in_sizes; (void)n_in; (void)out_size; (void)ws_size;
}

// Round 5
// 216.789 us; speedup vs baseline: 1.3567x; 1.3567x over previous
//
#include <hip/hip_runtime.h>
#include <math.h>

#define BATCH 256
#define CIN   512
#define CP    256
#define HW    361
#define NOUT  6

typedef short bf16x8 __attribute__((ext_vector_type(8)));
typedef float f32x4  __attribute__((ext_vector_type(4)));

__device__ __forceinline__ short f2bf(float f) {
    unsigned u = __float_as_uint(f);
    u += 0x7fffu + ((u >> 16) & 1u);
    return (short)(u >> 16);
}
__device__ __forceinline__ float bf2f(short s) {
    return __uint_as_float(((unsigned)(unsigned short)s) << 16);
}
// fast mish: mish(x) = x*(w-1)/(w+1), w=(1+e^x)^2.  Guard x>30 -> x (w overflow).
__device__ __forceinline__ float mish_f(float v) {
    float u = __expf(v);
    float a = 1.f + u;
    float w = a * a;
    float r = v * (w - 1.f) * __builtin_amdgcn_rcpf(w + 1.f);
    return (v > 30.f) ? v : r;
}
__device__ __forceinline__ void gl_lds16(const void* g, void* l) {
    __builtin_amdgcn_global_load_lds(
        (const __attribute__((address_space(1))) void*)g,
        (__attribute__((address_space(3))) void*)l, 16, 0, 0);
}

// ---------------------------------------------------------------------------
// K0a: weights f32 -> bf16, tiled + pre-swizzled [m(4)][kb(16)][row(128)][slot(4)*16B]
// rows 0-255 = w1p, 256-511 = w1g. Dest slot s holds source chunk s ^ ((row>>1)&3).
// ---------------------------------------------------------------------------
__global__ __launch_bounds__(256) void k0_weights(
    const float* __restrict__ w1p, const float* __restrict__ w1g,
    short* __restrict__ wT)
{
    int t = threadIdx.x;
    int r = blockIdx.x * 4 + (t >> 6);     // 0..511
    int cs = t & 63;                       // chunk-in-row: 64 x 8c
    int g = cs >> 2, s = cs & 3;           // kb group, dest slot
    int sc = s ^ ((r >> 1) & 3);           // source chunk
    const float* src = (r < 256) ? (w1p + (size_t)r * CIN)
                                 : (w1g + (size_t)(r - 256) * CIN);
    int c = g * 32 + sc * 8;
    float f[8];
    *(float4*)(f)     = *(const float4*)(src + c);
    *(float4*)(f + 4) = *(const float4*)(src + c + 4);
    bf16x8 v;
    #pragma unroll
    for (int i = 0; i < 8; ++i) v[i] = f2bf(f[i]);
    int m = r >> 7, rloc = r & 127;
    *(bf16x8*)((char*)wT + ((size_t)(m * 16 + g) * 128 + rloc) * 64 + s * 16) = v;
}

// ---------------------------------------------------------------------------
// K0b: x f32 [b][c][hw] -> bf16 tiled + pre-swizzled [b*3+n][kb16][row128][slot4*16B]
// One kb (32c x 128hw) per block: coalesced float4 reads -> LDS -> contiguous
// 1KB/wave swizzled writes. Grid (48 = n*16+kb, 256 = b).
// ---------------------------------------------------------------------------
__global__ __launch_bounds__(256) void k0_xpose(
    const float* __restrict__ x, short* __restrict__ xT)
{
    int nk = blockIdx.x;
    int n = nk >> 4, kb = nk & 15;
    int b = blockIdx.y;
    int t = threadIdx.x;
    int hw0 = n * 128;
    __shared__ float Ls[32][132];

    const float* xb = x + ((size_t)b * CIN + kb * 32) * HW;
    #pragma unroll
    for (int pss = 0; pss < 4; ++pss) {
        int idx = pss * 256 + t;
        int c = idx >> 5;                 // 0..31
        int hwc = (idx & 31) * 4;         // 0..124
        int hwg = hw0 + hwc;
        const float* src = xb + (size_t)c * HW + hwg;
        float4 v;
        if (hwg + 3 < HW) {
            v = *(const float4*)src;
        } else {
            v.x = (hwg     < HW) ? src[0] : 0.f;
            v.y = (hwg + 1 < HW) ? src[1] : 0.f;
            v.z = (hwg + 2 < HW) ? src[2] : 0.f;
            v.w = (hwg + 3 < HW) ? src[3] : 0.f;
        }
        *(float4*)&Ls[c][hwc] = v;
    }
    __syncthreads();

    char* dstb = (char*)xT + (size_t)(b * 3 + n) * 131072 + kb * 8192;
    #pragma unroll
    for (int cc = 0; cc < 2; ++cc) {
        int chunk = cc * 256 + t;         // 0..511, wave-contiguous
        int row = chunk >> 2;             // 0..127
        int s = chunk & 3;
        int sc = s ^ ((row >> 1) & 3);
        bf16x8 o;
        #pragma unroll
        for (int i = 0; i < 8; ++i) o[i] = f2bf(Ls[sc * 8 + i][row]);
        *(bf16x8*)(dstb + chunk * 16) = o;
    }
}

// ---------------------------------------------------------------------------
// K1: fused conv1p+conv1g bf16 MFMA GEMM.
// BK=32, TRIPLE-buffered LDS (3 x 16KB = 48KB -> 3 blocks/CU), prefetch depth
// 2 with counted vmcnt (steady: 12 outstanding, wait to 8), raw s_barrier,
// setprio around MFMA. Grid 3072, XCD-bijective remap, m fastest.
// ---------------------------------------------------------------------------
#define STAGE3(buf, p)                                                     \
    do {                                                                   \
        const char* ga_ = Ab + (p) * 8192;                                 \
        const char* gb_ = Bb + (p) * 8192;                                 \
        char* al_ = ((char*)As) + (buf) * 8192 + wid * 2048;               \
        char* bl_ = ((char*)Bs) + (buf) * 8192 + wid * 2048;               \
        gl_lds16(ga_,        al_);                                         \
        gl_lds16(ga_ + 1024, al_ + 1024);                                  \
        gl_lds16(gb_,        bl_);                                         \
        gl_lds16(gb_ + 1024, bl_ + 1024);                                  \
    } while (0)

__global__ __launch_bounds__(256, 3) void k1_conv1(
    const short* __restrict__ wT, const short* __restrict__ xT,
    const float* __restrict__ mask, const float* __restrict__ beta_g,
    short* __restrict__ outp_pre, float* __restrict__ psum, float* __restrict__ pmax)
{
    int orig = blockIdx.x;
    int newid = (orig & 7) * 384 + (orig >> 3);   // 3072 = 8 * 384, bijective
    int m = newid & 3;
    int nb = newid >> 2;          // b*3 + n
    int n = nb % 3;
    int b = nb / 3;

    const int tid = threadIdx.x;
    const int lane = tid & 63, wid = tid >> 6;
    const int wm = wid >> 1, wn = wid & 1;
    const int lc = lane & 15, lg = lane >> 4;
    const int hw0 = n * 128;

    __shared__ __align__(16) short As[3][4096];   // 3 x 8KB
    __shared__ __align__(16) short Bs[3][4096];
    __shared__ float maskS[128], betaS[128];
    // epilogue scratch overlays As (dead after main loop)
    float* redS = (float*)(&As[0][0]);
    float* redM = redS + 256;

    if (tid < 128) {
        int hwg = hw0 + tid;
        maskS[tid] = (hwg < HW) ? mask[b * HW + hwg] : 0.f;
        betaS[tid] = (m >= 2) ? beta_g[(m - 2) * 128 + tid] : 0.f;
    }
    // drain so counted vmcnt below starts from 0 outstanding
    asm volatile("s_waitcnt vmcnt(0) lgkmcnt(0)" ::: "memory");
    __builtin_amdgcn_sched_barrier(0);

    const char* Ab = (const char*)wT + (size_t)m * 131072 + wid * 2048 + lane * 16;
    const char* Bb = (const char*)xT + (size_t)nb * 131072 + wid * 2048 + lane * 16;

    f32x4 acc[4][4];
    #pragma unroll
    for (int i = 0; i < 4; ++i)
        #pragma unroll
        for (int j = 0; j < 4; ++j)
            acc[i][j] = (f32x4){0.f, 0.f, 0.f, 0.f};

    STAGE3(0, 0);
    STAGE3(1, 1);
    STAGE3(2, 2);
    asm volatile("s_waitcnt vmcnt(8)" ::: "memory");   // stage0's 4 done
    __builtin_amdgcn_sched_barrier(0);
    __builtin_amdgcn_s_barrier();

    #pragma unroll
    for (int p = 0; p < 16; ++p) {
        const int buf = p % 3;
        const char* ab = (const char*)As + buf * 8192;
        const char* bb = (const char*)Bs + buf * 8192;
        __builtin_amdgcn_s_setprio(1);
        {
            bf16x8 aF[4], bF[4];
            #pragma unroll
            for (int mf = 0; mf < 4; ++mf) {
                int r = wm * 64 + mf * 16 + lc;
                aF[mf] = *(const bf16x8*)(ab + r * 64 + ((lg ^ ((r >> 1) & 3)) * 16));
            }
            #pragma unroll
            for (int nf = 0; nf < 4; ++nf) {
                int r = wn * 64 + nf * 16 + lc;
                bF[nf] = *(const bf16x8*)(bb + r * 64 + ((lg ^ ((r >> 1) & 3)) * 16));
            }
            #pragma unroll
            for (int mf = 0; mf < 4; ++mf)
                #pragma unroll
                for (int nf = 0; nf < 4; ++nf)
                    acc[mf][nf] = __builtin_amdgcn_mfma_f32_16x16x32_bf16(
                        aF[mf], bF[nf], acc[mf][nf], 0, 0, 0);
        }
        __builtin_amdgcn_s_setprio(0);
        __builtin_amdgcn_s_barrier();          // all waves done reading buf
        if (p <= 12) {
            STAGE3(buf, p + 3);
            asm volatile("s_waitcnt vmcnt(8)" ::: "memory");  // stage p+1 done
            __builtin_amdgcn_sched_barrier(0);
            __builtin_amdgcn_s_barrier();
        } else if (p == 13) {
            asm volatile("s_waitcnt vmcnt(4)" ::: "memory");  // stage 14 done
            __builtin_amdgcn_sched_barrier(0);
            __builtin_amdgcn_s_barrier();
        } else if (p == 14) {
            asm volatile("s_waitcnt vmcnt(0)" ::: "memory");  // stage 15 done
            __builtin_amdgcn_sched_barrier(0);
            __builtin_amdgcn_s_barrier();
        }
    }
    __syncthreads();   // As reuse as redS/redM below

    if (m < 2) {
        // p-branch: store pre-activation conv1p output (bf16)
        #pragma unroll
        for (int mf = 0; mf < 4; ++mf) {
            int ch = m * 128 + wm * 64 + mf * 16 + lg * 4;
            #pragma unroll
            for (int nf = 0; nf < 4; ++nf) {
                int hw = hw0 + wn * 64 + nf * 16 + lc;
                if (hw < HW) {
                    #pragma unroll
                    for (int j = 0; j < 4; ++j)
                        outp_pre[((size_t)(b * CP + ch + j)) * HW + hw] = f2bf(acc[mf][nf][j]);
                }
            }
        }
    } else {
        // g-branch: mish((acc+beta)*mask); per-channel sum & max partials
        #pragma unroll
        for (int mf = 0; mf < 4; ++mf) {
            #pragma unroll
            for (int j = 0; j < 4; ++j) {
                int rloc = wm * 64 + mf * 16 + lg * 4 + j;
                float beta = betaS[rloc];
                float s = 0.f, mx = -INFINITY;
                #pragma unroll
                for (int nf = 0; nf < 4; ++nf) {
                    int cl = wn * 64 + nf * 16 + lc;
                    int hw = hw0 + cl;
                    float mv = maskS[cl];
                    float val = mish_f((acc[mf][nf][j] + beta) * mv);
                    if (hw < HW) {
                        s += val * mv;
                        mx = fmaxf(mx, val + mv - 1.f);
                    }
                }
                #pragma unroll
                for (int off = 1; off < 16; off <<= 1) {
                    s += __shfl_xor(s, off, 64);
                    mx = fmaxf(mx, __shfl_xor(mx, off, 64));
                }
                if (lc == 0) { redS[rloc * 2 + wn] = s; redM[rloc * 2 + wn] = mx; }
            }
        }
        __syncthreads();
        if (tid < 128) {
            int ch = (m - 2) * 128 + tid;
            float s = redS[tid * 2] + redS[tid * 2 + 1];
            float mx = fmaxf(redM[tid * 2], redM[tid * 2 + 1]);
            psum[((size_t)(b * CP + ch)) * 3 + n] = s;
            pmax[((size_t)(b * CP + ch)) * 3 + n] = mx;
        }
    }
}

// ---------------------------------------------------------------------------
// K2: per-batch pooled vector + linear_g. Grid 256 blocks x 256 threads.
// ---------------------------------------------------------------------------
__global__ __launch_bounds__(256) void k2_pool_linear(
    const float* __restrict__ mask, const float* __restrict__ psum,
    const float* __restrict__ pmax, const float* __restrict__ lw,
    float* __restrict__ g_out)
{
    int b = blockIdx.x, t = threadIdx.x;
    __shared__ float pooled[768];
    __shared__ float msr[4];

    float s = 0.f;
    for (int i = t; i < HW; i += 256) s += mask[b * HW + i];
    #pragma unroll
    for (int off = 1; off < 64; off <<= 1) s += __shfl_xor(s, off, 64);
    if ((t & 63) == 0) msr[t >> 6] = s;
    __syncthreads();
    float msum = msr[0] + msr[1] + msr[2] + msr[3];

    {
        int c = t;
        const float* ps = psum + (size_t)(b * CP + c) * 3;
        const float* pm = pmax + (size_t)(b * CP + c) * 3;
        float s3 = ps[0] + ps[1] + ps[2];
        float m3 = fmaxf(fmaxf(pm[0], pm[1]), pm[2]);
        float mean = s3 / msum;
        float sq = (sqrtf(msum) - 14.f) * 0.1f;
        pooled[c] = mean; pooled[256 + c] = mean * sq; pooled[512 + c] = m3;
    }
    __syncthreads();
    {
        int o = t;
        const float* wrow = lw + (size_t)o * 768;
        float acc = 0.f;
        #pragma unroll 4
        for (int j = 0; j < 768; ++j) acc += pooled[j] * wrow[j];
        g_out[b * CP + o] = acc;
    }
}

// ---------------------------------------------------------------------------
// K3: final fused mish((outp_pre+g+beta2)*mask) -> conv2p -> mask bias.
// outp_pre is bf16. Grid (6 hw-tiles, 256 b) x 256 threads.
// ---------------------------------------------------------------------------
__global__ __launch_bounds__(256) void k3_final(
    const short* __restrict__ outp_pre, const float* __restrict__ mask,
    const float* __restrict__ g_out, const float* __restrict__ beta2,
    const float* __restrict__ w2, float* __restrict__ out)
{
    int ht = blockIdx.x, b = blockIdx.y;
    int t = threadIdx.x;
    __shared__ float w2S[NOUT * 256];
    __shared__ float gbS[256];
    __shared__ float part[NOUT][256];

    for (int i = t; i < NOUT * 256; i += 256) w2S[i] = w2[i];
    gbS[t] = g_out[b * CP + t] + beta2[t];
    __syncthreads();

    int hw = t & 63, cg = t >> 6;
    int hwg = ht * 64 + hw;
    bool valid = hwg < HW;
    float maskv = valid ? mask[b * HW + hwg] : 0.f;

    float acc[NOUT] = {0.f, 0.f, 0.f, 0.f, 0.f, 0.f};
    const short* src = outp_pre + ((size_t)(b * CP + cg * 64)) * HW + hwg;
    #pragma unroll 4
    for (int ci = 0; ci < 64; ++ci) {
        float v = valid ? bf2f(src[(size_t)ci * HW]) : 0.f;
        float mm = mish_f((v + gbS[cg * 64 + ci]) * maskv);
        #pragma unroll
        for (int o = 0; o < NOUT; ++o) acc[o] += mm * w2S[o * 256 + cg * 64 + ci];
    }
    #pragma unroll
    for (int o = 0; o < NOUT; ++o) part[o][t] = acc[o];
    __syncthreads();

    for (int idx = t; idx < NOUT * 64; idx += 256) {
        int o = idx >> 6, h2 = idx & 63;
        int hg = ht * 64 + h2;
        if (hg < HW) {
            float mv = mask[b * HW + hg];
            float sum = part[o][h2] + part[o][64 + h2] + part[o][128 + h2] + part[o][192 + h2];
            out[((size_t)(b * NOUT + o)) * HW + hg] = sum - (1.f - mv) * 5000.f;
        }
    }
}

extern "C" void kernel_launch(void* const* d_in, const int* in_sizes, int n_in,
                              void* d_out, int out_size, void* d_ws, size_t ws_size,
                              hipStream_t stream) {
    const float* x     = (const float*)d_in[0];
    const float* mask  = (const float*)d_in[1];
    const float* w1p   = (const float*)d_in[2];
    const float* w1g   = (const float*)d_in[3];
    const float* betag = (const float*)d_in[4];
    const float* lw    = (const float*)d_in[5];
    const float* beta2 = (const float*)d_in[6];
    const float* w2    = (const float*)d_in[7];
    float* out = (float*)d_out;

    char* ws = (char*)d_ws;
    short* outp_pre = (short*)(ws);                      // 256*256*361*2 = 47,316,992 B
    short* xT       = (short*)(ws + 47316992);           // 768*131072    = 100,663,296 B
    short* wT       = (short*)(ws + 147980288);          // 4*131072      =     524,288 B
    float* psum     = (float*)(ws + 148504576);          // 256*256*3*4   =     786,432 B
    float* pmax     = (float*)(ws + 149291008);          // 256*256*3*4   =     786,432 B
    float* g_out    = (float*)(ws + 150077440);          // 256*256*4     =     262,144 B

    hipLaunchKernelGGL(k0_weights, dim3(128), dim3(256), 0, stream, w1p, w1g, wT);
    hipLaunchKernelGGL(k0_xpose, dim3(48, BATCH), dim3(256), 0, stream, x, xT);
    hipLaunchKernelGGL(k1_conv1, dim3(3072), dim3(256), 0, stream,
                       wT, xT, mask, betag, outp_pre, psum, pmax);
    hipLaunchKernelGGL(k2_pool_linear, dim3(BATCH), dim3(256), 0, stream,
                       mask, psum, pmax, lw, g_out);
    hipLaunchKernelGGL(k3_final, dim3(6, BATCH), dim3(256), 0, stream,
                       outp_pre, mask, g_out, beta2, w2, out);
    (void)in_sizes; (void)n_in; (void)out_size; (void)ws_size;
}

// Round 6
// 205.366 us; speedup vs baseline: 1.4322x; 1.0556x over previous
//
#include <hip/hip_runtime.h>
#include <math.h>

#define BATCH 256
#define CIN   512
#define CP    256
#define HW    361
#define NOUT  6

typedef short bf16x8 __attribute__((ext_vector_type(8)));
typedef float f32x4  __attribute__((ext_vector_type(4)));

__device__ __forceinline__ short f2bf(float f) {
    unsigned u = __float_as_uint(f);
    u += 0x7fffu + ((u >> 16) & 1u);
    return (short)(u >> 16);
}
__device__ __forceinline__ float bf2f(short s) {
    return __uint_as_float(((unsigned)(unsigned short)s) << 16);
}
// fast mish: mish(x) = x*(w-1)/(w+1), w=(1+e^x)^2.  Guard x>30 -> x (w overflow).
__device__ __forceinline__ float mish_f(float v) {
    float u = __expf(v);
    float a = 1.f + u;
    float w = a * a;
    float r = v * (w - 1.f) * __builtin_amdgcn_rcpf(w + 1.f);
    return (v > 30.f) ? v : r;
}
__device__ __forceinline__ void gl_lds16(const void* g, void* l) {
    __builtin_amdgcn_global_load_lds(
        (const __attribute__((address_space(1))) void*)g,
        (__attribute__((address_space(3))) void*)l, 16, 0, 0);
}

// ---------------------------------------------------------------------------
// K0a: weights f32 -> bf16, tiled + pre-swizzled [m(4)][kb(16)][row(128)][slot(4)*16B]
// rows 0-255 = w1p, 256-511 = w1g. Dest slot s holds source chunk s ^ ((row>>1)&3).
// ---------------------------------------------------------------------------
__global__ __launch_bounds__(256) void k0_weights(
    const float* __restrict__ w1p, const float* __restrict__ w1g,
    short* __restrict__ wT)
{
    int t = threadIdx.x;
    int r = blockIdx.x * 4 + (t >> 6);     // 0..511
    int cs = t & 63;                       // chunk-in-row: 64 x 8c
    int g = cs >> 2, s = cs & 3;           // kb group, dest slot
    int sc = s ^ ((r >> 1) & 3);           // source chunk
    const float* src = (r < 256) ? (w1p + (size_t)r * CIN)
                                 : (w1g + (size_t)(r - 256) * CIN);
    int c = g * 32 + sc * 8;
    float f[8];
    *(float4*)(f)     = *(const float4*)(src + c);
    *(float4*)(f + 4) = *(const float4*)(src + c + 4);
    bf16x8 v;
    #pragma unroll
    for (int i = 0; i < 8; ++i) v[i] = f2bf(f[i]);
    int m = r >> 7, rloc = r & 127;
    *(bf16x8*)((char*)wT + ((size_t)(m * 16 + g) * 128 + rloc) * 64 + s * 16) = v;
}

// ---------------------------------------------------------------------------
// K0b: x f32 [b][c][hw] -> bf16 tiled + pre-swizzled [b*3+n][kb16][row128][slot4*16B]
// One kb (32c x 128hw) per block: coalesced float4 reads -> LDS -> contiguous
// 1KB/wave swizzled writes. Grid (48 = n*16+kb, 256 = b).
// ---------------------------------------------------------------------------
__global__ __launch_bounds__(256) void k0_xpose(
    const float* __restrict__ x, short* __restrict__ xT)
{
    int nk = blockIdx.x;
    int n = nk >> 4, kb = nk & 15;
    int b = blockIdx.y;
    int t = threadIdx.x;
    int hw0 = n * 128;
    __shared__ float Ls[32][132];

    const float* xb = x + ((size_t)b * CIN + kb * 32) * HW;
    #pragma unroll
    for (int pss = 0; pss < 4; ++pss) {
        int idx = pss * 256 + t;
        int c = idx >> 5;                 // 0..31
        int hwc = (idx & 31) * 4;         // 0..124
        int hwg = hw0 + hwc;
        const float* src = xb + (size_t)c * HW + hwg;
        float4 v;
        if (hwg + 3 < HW) {
            v = *(const float4*)src;
        } else {
            v.x = (hwg     < HW) ? src[0] : 0.f;
            v.y = (hwg + 1 < HW) ? src[1] : 0.f;
            v.z = (hwg + 2 < HW) ? src[2] : 0.f;
            v.w = (hwg + 3 < HW) ? src[3] : 0.f;
        }
        *(float4*)&Ls[c][hwc] = v;
    }
    __syncthreads();

    char* dstb = (char*)xT + (size_t)(b * 3 + n) * 131072 + kb * 8192;
    #pragma unroll
    for (int cc = 0; cc < 2; ++cc) {
        int chunk = cc * 256 + t;         // 0..511, wave-contiguous
        int row = chunk >> 2;             // 0..127
        int s = chunk & 3;
        int sc = s ^ ((row >> 1) & 3);
        bf16x8 o;
        #pragma unroll
        for (int i = 0; i < 8; ++i) o[i] = f2bf(Ls[sc * 8 + i][row]);
        *(bf16x8*)(dstb + chunk * 16) = o;
    }
}

// ---------------------------------------------------------------------------
// K1: fused conv1p+conv1g bf16 MFMA GEMM — template-style schedule.
// Tile 256(M) x 128(N), BK=64, 512 threads (8 waves: 4 wm x 2 wn, each 64x64).
// 3 LDS buffers (A 32KB + B 16KB each = 144KB -> 1 block/CU), ONE barrier +
// ONE counted vmcnt(6) per K-tile, stage-issues interleaved with MFMA phases.
// mh=0 block: all conv1p rows; mh=1: all conv1g rows.
// Grid 1536, XCD-bijective remap, mh fastest (pair shares one xT tile).
// ---------------------------------------------------------------------------
#define STAGE_A(buf, t)                                                    \
    do {                                                                   \
        _Pragma("unroll")                                                  \
        for (int l_ = 0; l_ < 4; ++l_) {                                   \
            gl_lds16(aSrc + (l_ & 1) * 131072 + ((t) * 2 + (l_ >> 1)) * 8192, \
                     aDst + (buf) * 32768 + l_ * 8192);                    \
        }                                                                  \
    } while (0)

#define STAGE_B(buf, t)                                                    \
    do {                                                                   \
        _Pragma("unroll")                                                  \
        for (int l_ = 0; l_ < 2; ++l_) {                                   \
            gl_lds16(bSrc + ((t) * 2 + l_) * 8192,                         \
                     bDst + (buf) * 16384 + l_ * 8192);                    \
        }                                                                  \
    } while (0)

__global__ __launch_bounds__(512, 2) void k1_conv1(
    const short* __restrict__ wT, const short* __restrict__ xT,
    const float* __restrict__ mask, const float* __restrict__ beta_g,
    short* __restrict__ outp_pre, float* __restrict__ psum, float* __restrict__ pmax)
{
    int orig = blockIdx.x;
    int newid = (orig & 7) * 192 + (orig >> 3);   // 1536 = 8 * 192, bijective
    int mh = newid & 1;
    int nb = newid >> 1;          // b*3 + n
    int n = nb % 3;
    int b = nb / 3;

    const int tid = threadIdx.x;
    const int lane = tid & 63, wid = tid >> 6;
    const int wm = wid >> 1, wn = wid & 1;        // 4 x 2 waves
    const int lc = lane & 15, lg = lane >> 4;
    const int hw0 = n * 128;

    __shared__ __align__(16) short As[3][16384];  // 3 x 32KB: [kh2][sl2][row128][64B]
    __shared__ __align__(16) short Bs[3][8192];   // 3 x 16KB: [kh2][row128][64B]
    __shared__ float maskS[128], betaS[256];
    float* redS = (float*)(&As[0][0]);            // epilogue overlay (g-branch)
    float* redM = redS + 512;

    if (tid < 128) {
        int hwg = hw0 + tid;
        maskS[tid] = (hwg < HW) ? mask[b * HW + hwg] : 0.f;
    }
    if (mh == 1 && tid < 256) betaS[tid] = beta_g[tid];
    // drain so counted vmcnt below starts from 0 outstanding
    asm volatile("s_waitcnt vmcnt(0) lgkmcnt(0)" ::: "memory");
    __builtin_amdgcn_sched_barrier(0);

    const char* aSrc = (const char*)wT + mh * 262144 + tid * 16;
    const char* bSrc = (const char*)xT + (size_t)nb * 131072 + tid * 16;
    char* aDst = (char*)As + tid * 16;
    char* bDst = (char*)Bs + tid * 16;

    // per-thread invariant fragment offsets
    const int slA = wm >> 1;
    int aOff[4], bOff[4];
    #pragma unroll
    for (int mf = 0; mf < 4; ++mf) {
        int rloc = (wm & 1) * 64 + mf * 16 + lc;
        aOff[mf] = slA * 8192 + rloc * 64 + ((lg ^ ((rloc >> 1) & 3)) * 16);
    }
    #pragma unroll
    for (int nf = 0; nf < 4; ++nf) {
        int r = wn * 64 + nf * 16 + lc;
        bOff[nf] = r * 64 + ((lg ^ ((r >> 1) & 3)) * 16);
    }

    f32x4 acc[4][4];
    #pragma unroll
    for (int i = 0; i < 4; ++i)
        #pragma unroll
        for (int j = 0; j < 4; ++j)
            acc[i][j] = (f32x4){0.f, 0.f, 0.f, 0.f};

    STAGE_A(0, 0); STAGE_B(0, 0);
    STAGE_A(1, 1); STAGE_B(1, 1);
    asm volatile("s_waitcnt vmcnt(6)" ::: "memory");   // tile0's 6 done
    __builtin_amdgcn_sched_barrier(0);
    __builtin_amdgcn_s_barrier();
    __builtin_amdgcn_sched_barrier(0);

    #pragma unroll
    for (int t = 0; t < 8; ++t) {
        const int buf = t % 3;
        const char* abuf = (const char*)As + buf * 32768;
        const char* bbuf = (const char*)Bs + buf * 16384;
        // ---- sub-phase 0 (kh=0): A-stage issue for t+2, frags, 16 MFMA
        if (t < 6) { const int sb = (t + 2) % 3; STAGE_A(sb, t + 2); }
        {
            bf16x8 aF[4], bF[4];
            #pragma unroll
            for (int mf = 0; mf < 4; ++mf)
                aF[mf] = *(const bf16x8*)(abuf + aOff[mf]);
            #pragma unroll
            for (int nf = 0; nf < 4; ++nf)
                bF[nf] = *(const bf16x8*)(bbuf + bOff[nf]);
            __builtin_amdgcn_s_setprio(1);
            #pragma unroll
            for (int mf = 0; mf < 4; ++mf)
                #pragma unroll
                for (int nf = 0; nf < 4; ++nf)
                    acc[mf][nf] = __builtin_amdgcn_mfma_f32_16x16x32_bf16(
                        aF[mf], bF[nf], acc[mf][nf], 0, 0, 0);
            __builtin_amdgcn_s_setprio(0);
        }
        // ---- sub-phase 1 (kh=1): B-stage issue for t+2, frags, 16 MFMA
        if (t < 6) { const int sb = (t + 2) % 3; STAGE_B(sb, t + 2); }
        {
            bf16x8 aF[4], bF[4];
            #pragma unroll
            for (int mf = 0; mf < 4; ++mf)
                aF[mf] = *(const bf16x8*)(abuf + 16384 + aOff[mf]);
            #pragma unroll
            for (int nf = 0; nf < 4; ++nf)
                bF[nf] = *(const bf16x8*)(bbuf + 8192 + bOff[nf]);
            __builtin_amdgcn_s_setprio(1);
            #pragma unroll
            for (int mf = 0; mf < 4; ++mf)
                #pragma unroll
                for (int nf = 0; nf < 4; ++nf)
                    acc[mf][nf] = __builtin_amdgcn_mfma_f32_16x16x32_bf16(
                        aF[mf], bF[nf], acc[mf][nf], 0, 0, 0);
            __builtin_amdgcn_s_setprio(0);
        }
        // ---- tile end: counted wait (stage t+1 complete) + single barrier
        if (t < 6) {
            asm volatile("s_waitcnt vmcnt(6)" ::: "memory");
        } else if (t == 6) {
            asm volatile("s_waitcnt vmcnt(0)" ::: "memory");
        }
        if (t < 7) {
            __builtin_amdgcn_sched_barrier(0);
            __builtin_amdgcn_s_barrier();
            __builtin_amdgcn_sched_barrier(0);
        }
    }
    __syncthreads();   // As reused as redS/redM below (g-branch)

    if (mh == 0) {
        // p-branch: store pre-activation conv1p output (bf16), full 256 ch
        #pragma unroll
        for (int mf = 0; mf < 4; ++mf) {
            int ch = wm * 64 + mf * 16 + lg * 4;
            #pragma unroll
            for (int nf = 0; nf < 4; ++nf) {
                int hw = hw0 + wn * 64 + nf * 16 + lc;
                if (hw < HW) {
                    #pragma unroll
                    for (int j = 0; j < 4; ++j)
                        outp_pre[((size_t)(b * CP + ch + j)) * HW + hw] = f2bf(acc[mf][nf][j]);
                }
            }
        }
    } else {
        // g-branch: mish((acc+beta)*mask); per-channel sum & max partials
        #pragma unroll
        for (int mf = 0; mf < 4; ++mf) {
            #pragma unroll
            for (int j = 0; j < 4; ++j) {
                int rloc = wm * 64 + mf * 16 + lg * 4 + j;   // 0..255 g-channel
                float beta = betaS[rloc];
                float s = 0.f, mx = -INFINITY;
                #pragma unroll
                for (int nf = 0; nf < 4; ++nf) {
                    int cl = wn * 64 + nf * 16 + lc;
                    int hw = hw0 + cl;
                    float mv = maskS[cl];
                    float val = mish_f((acc[mf][nf][j] + beta) * mv);
                    if (hw < HW) {
                        s += val * mv;
                        mx = fmaxf(mx, val + mv - 1.f);
                    }
                }
                #pragma unroll
                for (int off = 1; off < 16; off <<= 1) {
                    s += __shfl_xor(s, off, 64);
                    mx = fmaxf(mx, __shfl_xor(mx, off, 64));
                }
                if (lc == 0) { redS[rloc * 2 + wn] = s; redM[rloc * 2 + wn] = mx; }
            }
        }
        __syncthreads();
        if (tid < 256) {
            float s = redS[tid * 2] + redS[tid * 2 + 1];
            float mx = fmaxf(redM[tid * 2], redM[tid * 2 + 1]);
            psum[((size_t)(b * CP + tid)) * 3 + n] = s;
            pmax[((size_t)(b * CP + tid)) * 3 + n] = mx;
        }
    }
}

// ---------------------------------------------------------------------------
// K2: per-batch pooled vector + linear_g. Grid 256 blocks x 256 threads.
// ---------------------------------------------------------------------------
__global__ __launch_bounds__(256) void k2_pool_linear(
    const float* __restrict__ mask, const float* __restrict__ psum,
    const float* __restrict__ pmax, const float* __restrict__ lw,
    float* __restrict__ g_out)
{
    int b = blockIdx.x, t = threadIdx.x;
    __shared__ float pooled[768];
    __shared__ float msr[4];

    float s = 0.f;
    for (int i = t; i < HW; i += 256) s += mask[b * HW + i];
    #pragma unroll
    for (int off = 1; off < 64; off <<= 1) s += __shfl_xor(s, off, 64);
    if ((t & 63) == 0) msr[t >> 6] = s;
    __syncthreads();
    float msum = msr[0] + msr[1] + msr[2] + msr[3];

    {
        int c = t;
        const float* ps = psum + (size_t)(b * CP + c) * 3;
        const float* pm = pmax + (size_t)(b * CP + c) * 3;
        float s3 = ps[0] + ps[1] + ps[2];
        float m3 = fmaxf(fmaxf(pm[0], pm[1]), pm[2]);
        float mean = s3 / msum;
        float sq = (sqrtf(msum) - 14.f) * 0.1f;
        pooled[c] = mean; pooled[256 + c] = mean * sq; pooled[512 + c] = m3;
    }
    __syncthreads();
    {
        int o = t;
        const float4* wrow = (const float4*)(lw + (size_t)o * 768);
        float acc = 0.f;
        #pragma unroll 8
        for (int j = 0; j < 192; ++j) {
            float4 w4 = wrow[j];
            float4 p4 = *(const float4*)&pooled[j * 4];
            acc += p4.x * w4.x + p4.y * w4.y + p4.z * w4.z + p4.w * w4.w;
        }
        g_out[b * CP + o] = acc;
    }
}

// ---------------------------------------------------------------------------
// K3: final fused mish((outp_pre+g+beta2)*mask) -> conv2p -> mask bias.
// outp_pre is bf16. Grid (6 hw-tiles, 256 b) x 256 threads.
// ---------------------------------------------------------------------------
__global__ __launch_bounds__(256) void k3_final(
    const short* __restrict__ outp_pre, const float* __restrict__ mask,
    const float* __restrict__ g_out, const float* __restrict__ beta2,
    const float* __restrict__ w2, float* __restrict__ out)
{
    int ht = blockIdx.x, b = blockIdx.y;
    int t = threadIdx.x;
    __shared__ float w2S[NOUT * 256];
    __shared__ float gbS[256];
    __shared__ float part[NOUT][256];

    for (int i = t; i < NOUT * 256; i += 256) w2S[i] = w2[i];
    gbS[t] = g_out[b * CP + t] + beta2[t];
    __syncthreads();

    int hw = t & 63, cg = t >> 6;
    int hwg = ht * 64 + hw;
    bool valid = hwg < HW;
    float maskv = valid ? mask[b * HW + hwg] : 0.f;

    float acc[NOUT] = {0.f, 0.f, 0.f, 0.f, 0.f, 0.f};
    const short* src = outp_pre + ((size_t)(b * CP + cg * 64)) * HW + hwg;
    #pragma unroll 4
    for (int ci = 0; ci < 64; ++ci) {
        float v = valid ? bf2f(src[(size_t)ci * HW]) : 0.f;
        float mm = mish_f((v + gbS[cg * 64 + ci]) * maskv);
        #pragma unroll
        for (int o = 0; o < NOUT; ++o) acc[o] += mm * w2S[o * 256 + cg * 64 + ci];
    }
    #pragma unroll
    for (int o = 0; o < NOUT; ++o) part[o][t] = acc[o];
    __syncthreads();

    for (int idx = t; idx < NOUT * 64; idx += 256) {
        int o = idx >> 6, h2 = idx & 63;
        int hg = ht * 64 + h2;
        if (hg < HW) {
            float mv = mask[b * HW + hg];
            float sum = part[o][h2] + part[o][64 + h2] + part[o][128 + h2] + part[o][192 + h2];
            out[((size_t)(b * NOUT + o)) * HW + hg] = sum - (1.f - mv) * 5000.f;
        }
    }
}

extern "C" void kernel_launch(void* const* d_in, const int* in_sizes, int n_in,
                              void* d_out, int out_size, void* d_ws, size_t ws_size,
                              hipStream_t stream) {
    const float* x     = (const float*)d_in[0];
    const float* mask  = (const float*)d_in[1];
    const float* w1p   = (const float*)d_in[2];
    const float* w1g   = (const float*)d_in[3];
    const float* betag = (const float*)d_in[4];
    const float* lw    = (const float*)d_in[5];
    const float* beta2 = (const float*)d_in[6];
    const float* w2    = (const float*)d_in[7];
    float* out = (float*)d_out;

    char* ws = (char*)d_ws;
    short* outp_pre = (short*)(ws);                      // 256*256*361*2 = 47,316,992 B
    short* xT       = (short*)(ws + 47316992);           // 768*131072    = 100,663,296 B
    short* wT       = (short*)(ws + 147980288);          // 4*131072      =     524,288 B
    float* psum     = (float*)(ws + 148504576);          // 256*256*3*4   =     786,432 B
    float* pmax     = (float*)(ws + 149291008);          // 256*256*3*4   =     786,432 B
    float* g_out    = (float*)(ws + 150077440);          // 256*256*4     =     262,144 B

    hipLaunchKernelGGL(k0_weights, dim3(128), dim3(256), 0, stream, w1p, w1g, wT);
    hipLaunchKernelGGL(k0_xpose, dim3(48, BATCH), dim3(256), 0, stream, x, xT);
    hipLaunchKernelGGL(k1_conv1, dim3(1536), dim3(512), 0, stream,
                       wT, xT, mask, betag, outp_pre, psum, pmax);
    hipLaunchKernelGGL(k2_pool_linear, dim3(BATCH), dim3(256), 0, stream,
                       mask, psum, pmax, lw, g_out);
    hipLaunchKernelGGL(k3_final, dim3(6, BATCH), dim3(256), 0, stream,
                       outp_pre, mask, g_out, beta2, w2, out);
    (void)in_sizes; (void)n_in; (void)out_size; (void)ws_size;
}

// Round 7
// 202.452 us; speedup vs baseline: 1.4528x; 1.0144x over previous
//
#include <hip/hip_runtime.h>
#include <math.h>

#define BATCH 256
#define CIN   512
#define CP    256
#define HW    361
#define NOUT  6

typedef short bf16x8 __attribute__((ext_vector_type(8)));
typedef float f32x4  __attribute__((ext_vector_type(4)));

__device__ __forceinline__ short f2bf(float f) {
    unsigned u = __float_as_uint(f);
    u += 0x7fffu + ((u >> 16) & 1u);
    return (short)(u >> 16);
}
__device__ __forceinline__ float bf2f(short s) {
    return __uint_as_float(((unsigned)(unsigned short)s) << 16);
}
// fast mish: mish(x) = x*(w-1)/(w+1), w=(1+e^x)^2.  Guard x>30 -> x (w overflow).
__device__ __forceinline__ float mish_f(float v) {
    float u = __expf(v);
    float a = 1.f + u;
    float w = a * a;
    float r = v * (w - 1.f) * __builtin_amdgcn_rcpf(w + 1.f);
    return (v > 30.f) ? v : r;
}
__device__ __forceinline__ void gl_lds16(const void* g, void* l) {
    __builtin_amdgcn_global_load_lds(
        (const __attribute__((address_space(1))) void*)g,
        (__attribute__((address_space(3))) void*)l, 16, 0, 0);
}

// ---------------------------------------------------------------------------
// K0a: weights f32 -> bf16, tiled + pre-swizzled [m(4)][kb(16)][row(128)][slot(4)*16B]
// rows 0-255 = w1p, 256-511 = w1g. Dest slot s holds source chunk s ^ ((row>>1)&3).
// ---------------------------------------------------------------------------
__global__ __launch_bounds__(256) void k0_weights(
    const float* __restrict__ w1p, const float* __restrict__ w1g,
    short* __restrict__ wT)
{
    int t = threadIdx.x;
    int r = blockIdx.x * 4 + (t >> 6);     // 0..511
    int cs = t & 63;                       // chunk-in-row: 64 x 8c
    int g = cs >> 2, s = cs & 3;           // kb group, dest slot
    int sc = s ^ ((r >> 1) & 3);           // source chunk
    const float* src = (r < 256) ? (w1p + (size_t)r * CIN)
                                 : (w1g + (size_t)(r - 256) * CIN);
    int c = g * 32 + sc * 8;
    float f[8];
    *(float4*)(f)     = *(const float4*)(src + c);
    *(float4*)(f + 4) = *(const float4*)(src + c + 4);
    bf16x8 v;
    #pragma unroll
    for (int i = 0; i < 8; ++i) v[i] = f2bf(f[i]);
    int m = r >> 7, rloc = r & 127;
    *(bf16x8*)((char*)wT + ((size_t)(m * 16 + g) * 128 + rloc) * 64 + s * 16) = v;
}

// ---------------------------------------------------------------------------
// K0b: x f32 [b][c][hw] -> bf16 tiled + pre-swizzled [b*3+n][kb16][row128][slot4*16B]
// One kb (32c x 128hw) per block: coalesced float4 reads -> LDS -> contiguous
// 1KB/wave swizzled writes. Grid (48 = n*16+kb, 256 = b).
// ---------------------------------------------------------------------------
__global__ __launch_bounds__(256) void k0_xpose(
    const float* __restrict__ x, short* __restrict__ xT)
{
    int nk = blockIdx.x;
    int n = nk >> 4, kb = nk & 15;
    int b = blockIdx.y;
    int t = threadIdx.x;
    int hw0 = n * 128;
    __shared__ float Ls[32][132];

    const float* xb = x + ((size_t)b * CIN + kb * 32) * HW;
    #pragma unroll
    for (int pss = 0; pss < 4; ++pss) {
        int idx = pss * 256 + t;
        int c = idx >> 5;                 // 0..31
        int hwc = (idx & 31) * 4;         // 0..124
        int hwg = hw0 + hwc;
        const float* src = xb + (size_t)c * HW + hwg;
        float4 v;
        if (hwg + 3 < HW) {
            v = *(const float4*)src;
        } else {
            v.x = (hwg     < HW) ? src[0] : 0.f;
            v.y = (hwg + 1 < HW) ? src[1] : 0.f;
            v.z = (hwg + 2 < HW) ? src[2] : 0.f;
            v.w = (hwg + 3 < HW) ? src[3] : 0.f;
        }
        *(float4*)&Ls[c][hwc] = v;
    }
    __syncthreads();

    char* dstb = (char*)xT + (size_t)(b * 3 + n) * 131072 + kb * 8192;
    #pragma unroll
    for (int cc = 0; cc < 2; ++cc) {
        int chunk = cc * 256 + t;         // 0..511, wave-contiguous
        int row = chunk >> 2;             // 0..127
        int s = chunk & 3;
        int sc = s ^ ((row >> 1) & 3);
        bf16x8 o;
        #pragma unroll
        for (int i = 0; i < 8; ++i) o[i] = f2bf(Ls[sc * 8 + i][row]);
        *(bf16x8*)(dstb + chunk * 16) = o;
    }
}

// ---------------------------------------------------------------------------
// K1: fused conv1p+conv1g bf16 MFMA GEMM — fat-M geometry.
// Tile M=512 (ALL weight rows: 0-255 conv1p, 256-511 conv1g) x N=128, BK=32.
// 8 waves (4 wm x 2 wn), per-wave 128x64 output (8x4 frags, acc=128 VGPR):
// 12 ds_read_b128 per 32 MFMA per K-step. B-tile read ONCE (no mh pair).
// 3 LDS buffers (A 3x32KB + B 3x8KB = 120KB -> 1 block/CU), depth-2 prefetch,
// counted vmcnt(5), one barrier per K-step, setprio around MFMA cluster.
// Epilogue: wm<2 waves store conv1p while wm>=2 waves reduce conv1g.
// Grid 768 (= b*3+n), XCD-bijective remap.
// ---------------------------------------------------------------------------
#define STAGE(buf, p)                                                      \
    do {                                                                   \
        _Pragma("unroll")                                                  \
        for (int l_ = 0; l_ < 4; ++l_) {                                   \
            gl_lds16(aSrc + l_ * 131072 + (p) * 8192,                      \
                     aDst + (buf) * 32768 + l_ * 8192);                    \
        }                                                                  \
        gl_lds16(bSrc + (p) * 8192, bDst + (buf) * 8192);                  \
    } while (0)

__global__ __launch_bounds__(512, 2) void k1_conv1(
    const short* __restrict__ wT, const short* __restrict__ xT,
    const float* __restrict__ mask, const float* __restrict__ beta_g,
    short* __restrict__ outp_pre, float* __restrict__ psum, float* __restrict__ pmax)
{
    int orig = blockIdx.x;
    int nb = (orig & 7) * 96 + (orig >> 3);   // 768 = 8 * 96, bijective
    int n = nb % 3;
    int b = nb / 3;

    const int tid = threadIdx.x;
    const int lane = tid & 63, wid = tid >> 6;
    const int wm = wid >> 1, wn = wid & 1;        // 4 x 2 waves
    const int lc = lane & 15, lg = lane >> 4;
    const int hw0 = n * 128;

    __shared__ __align__(16) short As[3][16384];  // 3 x 32KB: [row512][64B]
    __shared__ __align__(16) short Bs[3][4096];   // 3 x  8KB: [row128][64B]
    __shared__ float maskS[128], betaS[256];
    float* redS = (float*)(&As[0][0]);            // epilogue overlay
    float* redM = redS + 512;

    if (tid < 128) {
        int hwg = hw0 + tid;
        maskS[tid] = (hwg < HW) ? mask[b * HW + hwg] : 0.f;
    }
    if (tid < 256) betaS[tid] = beta_g[tid];
    // drain so counted vmcnt below starts from 0 outstanding
    asm volatile("s_waitcnt vmcnt(0) lgkmcnt(0)" ::: "memory");
    __builtin_amdgcn_sched_barrier(0);

    const char* aSrc = (const char*)wT + tid * 16;
    const char* bSrc = (const char*)xT + (size_t)nb * 131072 + tid * 16;
    char* aDst = (char*)As + tid * 16;
    char* bDst = (char*)Bs + tid * 16;

    // per-thread invariant fragment byte-offsets
    int aOff[8], bOff[4];
    #pragma unroll
    for (int mf = 0; mf < 8; ++mf) {
        int r = wm * 128 + mf * 16 + lc;          // 0..511
        aOff[mf] = r * 64 + ((lg ^ ((r >> 1) & 3)) * 16);
    }
    #pragma unroll
    for (int nf = 0; nf < 4; ++nf) {
        int r = wn * 64 + nf * 16 + lc;           // 0..127
        bOff[nf] = r * 64 + ((lg ^ ((r >> 1) & 3)) * 16);
    }

    f32x4 acc[8][4];
    #pragma unroll
    for (int i = 0; i < 8; ++i)
        #pragma unroll
        for (int j = 0; j < 4; ++j)
            acc[i][j] = (f32x4){0.f, 0.f, 0.f, 0.f};

    STAGE(0, 0);
    STAGE(1, 1);
    asm volatile("s_waitcnt vmcnt(5)" ::: "memory");   // stage0's 5 done
    __builtin_amdgcn_sched_barrier(0);
    __builtin_amdgcn_s_barrier();
    __builtin_amdgcn_sched_barrier(0);

    #pragma unroll
    for (int t = 0; t < 16; ++t) {
        const int buf = t % 3;
        const char* ab = (const char*)As + buf * 32768;
        const char* bb = (const char*)Bs + buf * 8192;
        if (t < 14) { const int sb = (t + 2) % 3; STAGE(sb, t + 2); }
        {
            bf16x8 aF[8], bF[4];
            #pragma unroll
            for (int mf = 0; mf < 8; ++mf)
                aF[mf] = *(const bf16x8*)(ab + aOff[mf]);
            #pragma unroll
            for (int nf = 0; nf < 4; ++nf)
                bF[nf] = *(const bf16x8*)(bb + bOff[nf]);
            __builtin_amdgcn_s_setprio(1);
            #pragma unroll
            for (int mf = 0; mf < 8; ++mf)
                #pragma unroll
                for (int nf = 0; nf < 4; ++nf)
                    acc[mf][nf] = __builtin_amdgcn_mfma_f32_16x16x32_bf16(
                        aF[mf], bF[nf], acc[mf][nf], 0, 0, 0);
            __builtin_amdgcn_s_setprio(0);
        }
        if (t < 14) {
            asm volatile("s_waitcnt vmcnt(5)" ::: "memory");   // stage t+1 done
        } else if (t == 14) {
            asm volatile("s_waitcnt vmcnt(0)" ::: "memory");   // stage 15 done
        }
        if (t < 15) {
            __builtin_amdgcn_sched_barrier(0);
            __builtin_amdgcn_s_barrier();
            __builtin_amdgcn_sched_barrier(0);
        }
    }
    __syncthreads();   // all LDS reads done; As reused as redS/redM

    if (wm < 2) {
        // p-waves: store pre-activation conv1p output (bf16), rows 0..255
        #pragma unroll
        for (int mf = 0; mf < 8; ++mf) {
            int ch = wm * 128 + mf * 16 + lg * 4;
            #pragma unroll
            for (int nf = 0; nf < 4; ++nf) {
                int hw = hw0 + wn * 64 + nf * 16 + lc;
                if (hw < HW) {
                    #pragma unroll
                    for (int j = 0; j < 4; ++j)
                        outp_pre[((size_t)(b * CP + ch + j)) * HW + hw] = f2bf(acc[mf][nf][j]);
                }
            }
        }
    } else {
        // g-waves: mish((acc+beta)*mask); per-channel sum & max partials
        #pragma unroll
        for (int mf = 0; mf < 8; ++mf) {
            #pragma unroll
            for (int j = 0; j < 4; ++j) {
                int rloc = (wm - 2) * 128 + mf * 16 + lg * 4 + j;   // 0..255
                float beta = betaS[rloc];
                float s = 0.f, mx = -INFINITY;
                #pragma unroll
                for (int nf = 0; nf < 4; ++nf) {
                    int cl = wn * 64 + nf * 16 + lc;
                    int hw = hw0 + cl;
                    float mv = maskS[cl];
                    float val = mish_f((acc[mf][nf][j] + beta) * mv);
                    if (hw < HW) {
                        s += val * mv;
                        mx = fmaxf(mx, val + mv - 1.f);
                    }
                }
                #pragma unroll
                for (int off = 1; off < 16; off <<= 1) {
                    s += __shfl_xor(s, off, 64);
                    mx = fmaxf(mx, __shfl_xor(mx, off, 64));
                }
                if (lc == 0) { redS[rloc * 2 + wn] = s; redM[rloc * 2 + wn] = mx; }
            }
        }
    }
    __syncthreads();
    if (tid < 256) {
        float s = redS[tid * 2] + redS[tid * 2 + 1];
        float mx = fmaxf(redM[tid * 2], redM[tid * 2 + 1]);
        psum[((size_t)(b * CP + tid)) * 3 + n] = s;
        pmax[((size_t)(b * CP + tid)) * 3 + n] = mx;
    }
}

// ---------------------------------------------------------------------------
// K2: per-batch pooled vector + linear_g. Grid 256 blocks x 256 threads.
// ---------------------------------------------------------------------------
__global__ __launch_bounds__(256) void k2_pool_linear(
    const float* __restrict__ mask, const float* __restrict__ psum,
    const float* __restrict__ pmax, const float* __restrict__ lw,
    float* __restrict__ g_out)
{
    int b = blockIdx.x, t = threadIdx.x;
    __shared__ float pooled[768];
    __shared__ float msr[4];

    float s = 0.f;
    for (int i = t; i < HW; i += 256) s += mask[b * HW + i];
    #pragma unroll
    for (int off = 1; off < 64; off <<= 1) s += __shfl_xor(s, off, 64);
    if ((t & 63) == 0) msr[t >> 6] = s;
    __syncthreads();
    float msum = msr[0] + msr[1] + msr[2] + msr[3];

    {
        int c = t;
        const float* ps = psum + (size_t)(b * CP + c) * 3;
        const float* pm = pmax + (size_t)(b * CP + c) * 3;
        float s3 = ps[0] + ps[1] + ps[2];
        float m3 = fmaxf(fmaxf(pm[0], pm[1]), pm[2]);
        float mean = s3 / msum;
        float sq = (sqrtf(msum) - 14.f) * 0.1f;
        pooled[c] = mean; pooled[256 + c] = mean * sq; pooled[512 + c] = m3;
    }
    __syncthreads();
    {
        int o = t;
        const float4* wrow = (const float4*)(lw + (size_t)o * 768);
        float acc = 0.f;
        #pragma unroll 8
        for (int j = 0; j < 192; ++j) {
            float4 w4 = wrow[j];
            float4 p4 = *(const float4*)&pooled[j * 4];
            acc += p4.x * w4.x + p4.y * w4.y + p4.z * w4.z + p4.w * w4.w;
        }
        g_out[b * CP + o] = acc;
    }
}

// ---------------------------------------------------------------------------
// K3: final fused mish((outp_pre+g+beta2)*mask) -> conv2p -> mask bias.
// outp_pre is bf16. Grid (6 hw-tiles, 256 b) x 256 threads.
// ---------------------------------------------------------------------------
__global__ __launch_bounds__(256) void k3_final(
    const short* __restrict__ outp_pre, const float* __restrict__ mask,
    const float* __restrict__ g_out, const float* __restrict__ beta2,
    const float* __restrict__ w2, float* __restrict__ out)
{
    int ht = blockIdx.x, b = blockIdx.y;
    int t = threadIdx.x;
    __shared__ float w2S[NOUT * 256];
    __shared__ float gbS[256];
    __shared__ float part[NOUT][256];

    for (int i = t; i < NOUT * 256; i += 256) w2S[i] = w2[i];
    gbS[t] = g_out[b * CP + t] + beta2[t];
    __syncthreads();

    int hw = t & 63, cg = t >> 6;
    int hwg = ht * 64 + hw;
    bool valid = hwg < HW;
    float maskv = valid ? mask[b * HW + hwg] : 0.f;

    float acc[NOUT] = {0.f, 0.f, 0.f, 0.f, 0.f, 0.f};
    const short* src = outp_pre + ((size_t)(b * CP + cg * 64)) * HW + hwg;
    #pragma unroll 4
    for (int ci = 0; ci < 64; ++ci) {
        float v = valid ? bf2f(src[(size_t)ci * HW]) : 0.f;
        float mm = mish_f((v + gbS[cg * 64 + ci]) * maskv);
        #pragma unroll
        for (int o = 0; o < NOUT; ++o) acc[o] += mm * w2S[o * 256 + cg * 64 + ci];
    }
    #pragma unroll
    for (int o = 0; o < NOUT; ++o) part[o][t] = acc[o];
    __syncthreads();

    for (int idx = t; idx < NOUT * 64; idx += 256) {
        int o = idx >> 6, h2 = idx & 63;
        int hg = ht * 64 + h2;
        if (hg < HW) {
            float mv = mask[b * HW + hg];
            float sum = part[o][h2] + part[o][64 + h2] + part[o][128 + h2] + part[o][192 + h2];
            out[((size_t)(b * NOUT + o)) * HW + hg] = sum - (1.f - mv) * 5000.f;
        }
    }
}

extern "C" void kernel_launch(void* const* d_in, const int* in_sizes, int n_in,
                              void* d_out, int out_size, void* d_ws, size_t ws_size,
                              hipStream_t stream) {
    const float* x     = (const float*)d_in[0];
    const float* mask  = (const float*)d_in[1];
    const float* w1p   = (const float*)d_in[2];
    const float* w1g   = (const float*)d_in[3];
    const float* betag = (const float*)d_in[4];
    const float* lw    = (const float*)d_in[5];
    const float* beta2 = (const float*)d_in[6];
    const float* w2    = (const float*)d_in[7];
    float* out = (float*)d_out;

    char* ws = (char*)d_ws;
    short* outp_pre = (short*)(ws);                      // 256*256*361*2 = 47,316,992 B
    short* xT       = (short*)(ws + 47316992);           // 768*131072    = 100,663,296 B
    short* wT       = (short*)(ws + 147980288);          // 4*131072      =     524,288 B
    float* psum     = (float*)(ws + 148504576);          // 256*256*3*4   =     786,432 B
    float* pmax     = (float*)(ws + 149291008);          // 256*256*3*4   =     786,432 B
    float* g_out    = (float*)(ws + 150077440);          // 256*256*4     =     262,144 B

    hipLaunchKernelGGL(k0_weights, dim3(128), dim3(256), 0, stream, w1p, w1g, wT);
    hipLaunchKernelGGL(k0_xpose, dim3(48, BATCH), dim3(256), 0, stream, x, xT);
    hipLaunchKernelGGL(k1_conv1, dim3(768), dim3(512), 0, stream,
                       wT, xT, mask, betag, outp_pre, psum, pmax);
    hipLaunchKernelGGL(k2_pool_linear, dim3(BATCH), dim3(256), 0, stream,
                       mask, psum, pmax, lw, g_out);
    hipLaunchKernelGGL(k3_final, dim3(6, BATCH), dim3(256), 0, stream,
                       outp_pre, mask, g_out, beta2, w2, out);
    (void)in_sizes; (void)n_in; (void)out_size; (void)ws_size;
}

// Round 8
// 159.293 us; speedup vs baseline: 1.8465x; 1.2709x over previous
//
#include <hip/hip_runtime.h>
#include <math.h>

#define BATCH 256
#define CIN   512
#define CP    256
#define HW    361
#define NOUT  6

typedef short bf16x8 __attribute__((ext_vector_type(8)));
typedef float f32x4  __attribute__((ext_vector_type(4)));

__device__ __forceinline__ short f2bf(float f) {
    unsigned u = __float_as_uint(f);
    u += 0x7fffu + ((u >> 16) & 1u);
    return (short)(u >> 16);
}
__device__ __forceinline__ float bf2f(short s) {
    return __uint_as_float(((unsigned)(unsigned short)s) << 16);
}
// fast mish: mish(x) = x*(w-1)/(w+1), w=(1+e^x)^2.  Guard x>30 -> x (w overflow).
__device__ __forceinline__ float mish_f(float v) {
    float u = __expf(v);
    float a = 1.f + u;
    float w = a * a;
    float r = v * (w - 1.f) * __builtin_amdgcn_rcpf(w + 1.f);
    return (v > 30.f) ? v : r;
}
__device__ __forceinline__ void gl_lds16(const void* g, void* l) {
    __builtin_amdgcn_global_load_lds(
        (const __attribute__((address_space(1))) void*)g,
        (__attribute__((address_space(3))) void*)l, 16, 0, 0);
}

// ---------------------------------------------------------------------------
// K0a: weights f32 -> bf16, pre-swizzled [half2][kb16][row256][slot4*16B].
// half 0 = w1p rows, half 1 = w1g rows. Dest slot s holds source chunk
// sc = s ^ ((row>>1)&3). One 16B chunk per thread; grid 128 x 256.
// ---------------------------------------------------------------------------
__global__ __launch_bounds__(256) void k0_weights(
    const float* __restrict__ w1p, const float* __restrict__ w1g,
    short* __restrict__ wT)
{
    int g = blockIdx.x * 256 + threadIdx.x;   // 0..32767 chunk id
    int half = g >> 14;
    int kb   = (g >> 10) & 15;
    int row  = (g >> 2) & 255;
    int s    = g & 3;
    int sc   = s ^ ((row >> 1) & 3);
    const float* src = (half == 0) ? (w1p + (size_t)row * CIN)
                                   : (w1g + (size_t)row * CIN);
    int c = kb * 32 + sc * 8;
    float f[8];
    *(float4*)(f)     = *(const float4*)(src + c);
    *(float4*)(f + 4) = *(const float4*)(src + c + 4);
    bf16x8 v;
    #pragma unroll
    for (int i = 0; i < 8; ++i) v[i] = f2bf(f[i]);
    *(bf16x8*)((char*)wT + (size_t)half * 262144 + kb * 16384 + row * 64 + s * 16) = v;
}

// ---------------------------------------------------------------------------
// K1: fused transpose + conv1p/conv1g bf16 MFMA GEMM.
// Block = one half (p or g): M=256 x N=128(hw), BK=32, 512 thr (8 waves 4x2,
// per-wave 64x64, acc 64). A: global_load_lds from pre-swizzled wT, 3 bufs.
// B: reg-staged direct from x (8 f32/thread, coalesced over hw) -> cvt ->
// swizzled ds_write_b128, 2 bufs (write target never the buffer being read).
// One s_barrier per K-step; counted vmcnt(2)/vmcnt(10), never 0 mid-loop.
// LDS 64KB -> 2 resident blocks/CU. Grid 1536, XCD-bijective, half fastest.
// ---------------------------------------------------------------------------
__global__ __launch_bounds__(512, 4) void k1_conv1(
    const float* __restrict__ x, const short* __restrict__ wT,
    const float* __restrict__ mask, const float* __restrict__ beta_g,
    short* __restrict__ outp_pre, float* __restrict__ psum, float* __restrict__ pmax)
{
    int orig = blockIdx.x;
    int newid = (orig & 7) * 192 + (orig >> 3);   // 1536 = 8*192, bijective
    int half = newid & 1;
    int nb = newid >> 1;          // b*3 + n
    int n = nb % 3;
    int b = nb / 3;

    const int tid = threadIdx.x;
    const int lane = tid & 63, wid = tid >> 6;
    const int wm = wid >> 1, wn = wid & 1;        // 4 x 2 waves, 64x64 each
    const int lc = lane & 15, lg = lane >> 4;
    const int hw0 = n * 128;

    __shared__ __align__(16) short As[3][8192];   // 3 x 16KB [row256][64B]
    __shared__ __align__(16) short Bs[2][4096];   // 2 x  8KB [row128][64B]
    __shared__ float maskS[128], betaS[256];
    float* redS = (float*)(&As[0][0]);            // epilogue overlay (4KB)
    float* redM = redS + 512;

    if (tid < 128) {
        int hwg = hw0 + tid;
        maskS[tid] = (hwg < HW) ? mask[b * HW + hwg] : 0.f;
    }
    if (tid < 256) betaS[tid] = beta_g[tid];
    asm volatile("s_waitcnt vmcnt(0) lgkmcnt(0)" ::: "memory");
    __builtin_amdgcn_sched_barrier(0);

    // ---- B (x) staging geometry: thread -> (row=hw, slot) with pre-swizzle
    const int brow = tid & 127;            // hw within tile
    const int bs   = tid >> 7;             // dest slot 0..3
    const int bsc  = bs ^ ((brow >> 1) & 3);
    const int hwg  = hw0 + brow;
    const bool bvalid = hwg < HW;
    const float* xb = x + ((size_t)b * CIN + bsc * 8) * HW + hwg;   // + kb*32*HW per step
    char* bDstBase = (char*)Bs;            // + buf*8192 + brow*64 + bs*16

    // ---- A staging: 2 chunks/thread from wT
    const char* aSrc = (const char*)wT + (size_t)half * 262144 + tid * 16;
    char* aDst = (char*)As + tid * 16;

    // per-thread invariant fragment byte-offsets
    int aOff[4], bOff[4];
    #pragma unroll
    for (int mf = 0; mf < 4; ++mf) {
        int r = wm * 64 + mf * 16 + lc;            // 0..255
        aOff[mf] = r * 64 + ((lg ^ ((r >> 1) & 3)) * 16);
    }
    #pragma unroll
    for (int nf = 0; nf < 4; ++nf) {
        int r = wn * 64 + nf * 16 + lc;            // 0..127
        bOff[nf] = r * 64 + ((lg ^ ((r >> 1) & 3)) * 16);
    }

    float regB[8];
    #pragma unroll
    for (int i = 0; i < 8; ++i) regB[i] = 0.f;

    f32x4 acc[4][4];
    #pragma unroll
    for (int i = 0; i < 4; ++i)
        #pragma unroll
        for (int j = 0; j < 4; ++j)
            acc[i][j] = (f32x4){0.f, 0.f, 0.f, 0.f};

#define BLOAD(kb)                                                          \
    do {                                                                   \
        const float* src_ = xb + (size_t)(kb) * 32 * HW;                   \
        _Pragma("unroll")                                                  \
        for (int i_ = 0; i_ < 8; ++i_) {                                   \
            regB[i_] = bvalid ? src_[(size_t)i_ * HW] : 0.f;               \
        }                                                                  \
    } while (0)

#define BWRITE(buf)                                                        \
    do {                                                                   \
        bf16x8 o_;                                                         \
        _Pragma("unroll")                                                  \
        for (int i_ = 0; i_ < 8; ++i_) o_[i_] = f2bf(regB[i_]);            \
        *(bf16x8*)(bDstBase + (buf) * 8192 + brow * 64 + bs * 16) = o_;    \
    } while (0)

#define ALOAD(buf, kb)                                                     \
    do {                                                                   \
        gl_lds16(aSrc + (kb) * 16384,        aDst + (buf) * 16384);        \
        gl_lds16(aSrc + (kb) * 16384 + 8192, aDst + (buf) * 16384 + 8192); \
    } while (0)

    // ---- prologue: fill pipeline (invariant at loop top: stage(t+1) = 10 outstanding)
    BLOAD(0); ALOAD(0, 0);                       // 8 + 2 in flight
    asm volatile("s_waitcnt vmcnt(2)" ::: "memory");   // B(0) regs ready
    __builtin_amdgcn_sched_barrier(0);
    BWRITE(0);
    BLOAD(1); ALOAD(1, 1);                       // outstanding: A(0)2 + B(1)8 + A(1)2
    asm volatile("s_waitcnt vmcnt(10)" ::: "memory");  // A(0) in LDS
    __builtin_amdgcn_sched_barrier(0);
    asm volatile("s_waitcnt lgkmcnt(0)" ::: "memory");
    __builtin_amdgcn_s_barrier();
    __builtin_amdgcn_sched_barrier(0);

    #pragma unroll
    for (int t = 0; t < 16; ++t) {
        const int bufA = t % 3;
        const int bufB = t & 1;
        const char* ab = (const char*)As + bufA * 16384;
        const char* bb = (const char*)Bs + bufB * 8192;

        bf16x8 aF[4], bF[4];
        #pragma unroll
        for (int mf = 0; mf < 4; ++mf) aF[mf] = *(const bf16x8*)(ab + aOff[mf]);
        #pragma unroll
        for (int nf = 0; nf < 4; ++nf) bF[nf] = *(const bf16x8*)(bb + bOff[nf]);

        if (t < 15) {
            // B(t+1) regs -> LDS buffer NOT being read this phase
            asm volatile("s_waitcnt vmcnt(2)" ::: "memory");
            __builtin_amdgcn_sched_barrier(0);
            BWRITE((t + 1) & 1);
        }
        if (t < 14) {
            BLOAD(t + 2); ALOAD((t + 2) % 3, t + 2);
        }

        __builtin_amdgcn_s_setprio(1);
        #pragma unroll
        for (int mf = 0; mf < 4; ++mf)
            #pragma unroll
            for (int nf = 0; nf < 4; ++nf)
                acc[mf][nf] = __builtin_amdgcn_mfma_f32_16x16x32_bf16(
                    aF[mf], bF[nf], acc[mf][nf], 0, 0, 0);
        __builtin_amdgcn_s_setprio(0);

        if (t < 14) {
            asm volatile("s_waitcnt vmcnt(10)" ::: "memory");  // A(t+1) in LDS
        } else if (t == 14) {
            asm volatile("s_waitcnt vmcnt(0)" ::: "memory");
        }
        if (t < 15) {
            __builtin_amdgcn_sched_barrier(0);
            asm volatile("s_waitcnt lgkmcnt(0)" ::: "memory");
            __builtin_amdgcn_s_barrier();
            __builtin_amdgcn_sched_barrier(0);
        }
    }
    __syncthreads();   // LDS reads done; As reused as redS/redM

    if (half == 0) {
        // p-half: store pre-activation conv1p output (bf16), rows 0..255
        #pragma unroll
        for (int mf = 0; mf < 4; ++mf) {
            int ch = wm * 64 + mf * 16 + lg * 4;
            #pragma unroll
            for (int nf = 0; nf < 4; ++nf) {
                int hw = hw0 + wn * 64 + nf * 16 + lc;
                if (hw < HW) {
                    #pragma unroll
                    for (int j = 0; j < 4; ++j)
                        outp_pre[((size_t)(b * CP + ch + j)) * HW + hw] = f2bf(acc[mf][nf][j]);
                }
            }
        }
    } else {
        // g-half: mish((acc+beta)*mask); per-channel sum & max partials
        #pragma unroll
        for (int mf = 0; mf < 4; ++mf) {
            #pragma unroll
            for (int j = 0; j < 4; ++j) {
                int rloc = wm * 64 + mf * 16 + lg * 4 + j;   // 0..255
                float beta = betaS[rloc];
                float s = 0.f, mx = -INFINITY;
                #pragma unroll
                for (int nf = 0; nf < 4; ++nf) {
                    int cl = wn * 64 + nf * 16 + lc;
                    int hw = hw0 + cl;
                    float mv = maskS[cl];
                    float val = mish_f((acc[mf][nf][j] + beta) * mv);
                    if (hw < HW) {
                        s += val * mv;
                        mx = fmaxf(mx, val + mv - 1.f);
                    }
                }
                #pragma unroll
                for (int off = 1; off < 16; off <<= 1) {
                    s += __shfl_xor(s, off, 64);
                    mx = fmaxf(mx, __shfl_xor(mx, off, 64));
                }
                if (lc == 0) { redS[rloc * 2 + wn] = s; redM[rloc * 2 + wn] = mx; }
            }
        }
        __syncthreads();
        if (tid < 256) {
            float s = redS[tid * 2] + redS[tid * 2 + 1];
            float mx = fmaxf(redM[tid * 2], redM[tid * 2 + 1]);
            psum[((size_t)(b * CP + tid)) * 3 + n] = s;
            pmax[((size_t)(b * CP + tid)) * 3 + n] = mx;
        }
    }
#undef BLOAD
#undef BWRITE
#undef ALOAD
}

// ---------------------------------------------------------------------------
// K2: per-batch pooled vector + linear_g. Grid 256 blocks x 256 threads.
// ---------------------------------------------------------------------------
__global__ __launch_bounds__(256) void k2_pool_linear(
    const float* __restrict__ mask, const float* __restrict__ psum,
    const float* __restrict__ pmax, const float* __restrict__ lw,
    float* __restrict__ g_out)
{
    int b = blockIdx.x, t = threadIdx.x;
    __shared__ float pooled[768];
    __shared__ float msr[4];

    float s = 0.f;
    for (int i = t; i < HW; i += 256) s += mask[b * HW + i];
    #pragma unroll
    for (int off = 1; off < 64; off <<= 1) s += __shfl_xor(s, off, 64);
    if ((t & 63) == 0) msr[t >> 6] = s;
    __syncthreads();
    float msum = msr[0] + msr[1] + msr[2] + msr[3];

    {
        int c = t;
        const float* ps = psum + (size_t)(b * CP + c) * 3;
        const float* pm = pmax + (size_t)(b * CP + c) * 3;
        float s3 = ps[0] + ps[1] + ps[2];
        float m3 = fmaxf(fmaxf(pm[0], pm[1]), pm[2]);
        float mean = s3 / msum;
        float sq = (sqrtf(msum) - 14.f) * 0.1f;
        pooled[c] = mean; pooled[256 + c] = mean * sq; pooled[512 + c] = m3;
    }
    __syncthreads();
    {
        int o = t;
        const float4* wrow = (const float4*)(lw + (size_t)o * 768);
        float acc = 0.f;
        #pragma unroll 8
        for (int j = 0; j < 192; ++j) {
            float4 w4 = wrow[j];
            float4 p4 = *(const float4*)&pooled[j * 4];
            acc += p4.x * w4.x + p4.y * w4.y + p4.z * w4.z + p4.w * w4.w;
        }
        g_out[b * CP + o] = acc;
    }
}

// ---------------------------------------------------------------------------
// K3: final fused mish((outp_pre+g+beta2)*mask) -> conv2p -> mask bias.
// outp_pre is bf16. Grid (6 hw-tiles, 256 b) x 256 threads.
// ---------------------------------------------------------------------------
__global__ __launch_bounds__(256) void k3_final(
    const short* __restrict__ outp_pre, const float* __restrict__ mask,
    const float* __restrict__ g_out, const float* __restrict__ beta2,
    const float* __restrict__ w2, float* __restrict__ out)
{
    int ht = blockIdx.x, b = blockIdx.y;
    int t = threadIdx.x;
    __shared__ float w2S[NOUT * 256];
    __shared__ float gbS[256];
    __shared__ float part[NOUT][256];

    for (int i = t; i < NOUT * 256; i += 256) w2S[i] = w2[i];
    gbS[t] = g_out[b * CP + t] + beta2[t];
    __syncthreads();

    int hw = t & 63, cg = t >> 6;
    int hwg = ht * 64 + hw;
    bool valid = hwg < HW;
    float maskv = valid ? mask[b * HW + hwg] : 0.f;

    float acc[NOUT] = {0.f, 0.f, 0.f, 0.f, 0.f, 0.f};
    const short* src = outp_pre + ((size_t)(b * CP + cg * 64)) * HW + hwg;
    #pragma unroll 4
    for (int ci = 0; ci < 64; ++ci) {
        float v = valid ? bf2f(src[(size_t)ci * HW]) : 0.f;
        float mm = mish_f((v + gbS[cg * 64 + ci]) * maskv);
        #pragma unroll
        for (int o = 0; o < NOUT; ++o) acc[o] += mm * w2S[o * 256 + cg * 64 + ci];
    }
    #pragma unroll
    for (int o = 0; o < NOUT; ++o) part[o][t] = acc[o];
    __syncthreads();

    for (int idx = t; idx < NOUT * 64; idx += 256) {
        int o = idx >> 6, h2 = idx & 63;
        int hg = ht * 64 + h2;
        if (hg < HW) {
            float mv = mask[b * HW + hg];
            float sum = part[o][h2] + part[o][64 + h2] + part[o][128 + h2] + part[o][192 + h2];
            out[((size_t)(b * NOUT + o)) * HW + hg] = sum - (1.f - mv) * 5000.f;
        }
    }
}

extern "C" void kernel_launch(void* const* d_in, const int* in_sizes, int n_in,
                              void* d_out, int out_size, void* d_ws, size_t ws_size,
                              hipStream_t stream) {
    const float* x     = (const float*)d_in[0];
    const float* mask  = (const float*)d_in[1];
    const float* w1p   = (const float*)d_in[2];
    const float* w1g   = (const float*)d_in[3];
    const float* betag = (const float*)d_in[4];
    const float* lw    = (const float*)d_in[5];
    const float* beta2 = (const float*)d_in[6];
    const float* w2    = (const float*)d_in[7];
    float* out = (float*)d_out;

    char* ws = (char*)d_ws;
    short* outp_pre = (short*)(ws);                      // 256*256*361*2 = 47,316,992 B
    short* wT       = (short*)(ws + 47316992);           // 2*262144      =     524,288 B
    float* psum     = (float*)(ws + 47841280);           // 256*256*3*4   =     786,432 B
    float* pmax     = (float*)(ws + 48627712);           // 256*256*3*4   =     786,432 B
    float* g_out    = (float*)(ws + 49414144);           // 256*256*4     =     262,144 B

    hipLaunchKernelGGL(k0_weights, dim3(128), dim3(256), 0, stream, w1p, w1g, wT);
    hipLaunchKernelGGL(k1_conv1, dim3(1536), dim3(512), 0, stream,
                       x, wT, mask, betag, outp_pre, psum, pmax);
    hipLaunchKernelGGL(k2_pool_linear, dim3(BATCH), dim3(256), 0, stream,
                       mask, psum, pmax, lw, g_out);
    hipLaunchKernelGGL(k3_final, dim3(6, BATCH), dim3(256), 0, stream,
                       outp_pre, mask, g_out, beta2, w2, out);
    (void)in_sizes; (void)n_in; (void)out_size; (void)ws_size;
}

// Round 9
// 142.913 us; speedup vs baseline: 2.0581x; 1.1146x over previous
//
#include <hip/hip_runtime.h>
#include <math.h>

#define BATCH 256
#define CIN   512
#define CP    256
#define HW    361
#define NOUT  6

typedef short bf16x8 __attribute__((ext_vector_type(8)));
typedef float f32x4  __attribute__((ext_vector_type(4)));

__device__ __forceinline__ short f2bf(float f) {
    unsigned u = __float_as_uint(f);
    u += 0x7fffu + ((u >> 16) & 1u);
    return (short)(u >> 16);
}
__device__ __forceinline__ float bf2f(short s) {
    return __uint_as_float(((unsigned)(unsigned short)s) << 16);
}
// fast mish: mish(x) = x*(w-1)/(w+1), w=(1+e^x)^2.  Guard x>30 -> x (w overflow).
__device__ __forceinline__ float mish_f(float v) {
    float u = __expf(v);
    float a = 1.f + u;
    float w = a * a;
    float r = v * (w - 1.f) * __builtin_amdgcn_rcpf(w + 1.f);
    return (v > 30.f) ? v : r;
}
__device__ __forceinline__ void gl_lds16(const void* g, void* l) {
    __builtin_amdgcn_global_load_lds(
        (const __attribute__((address_space(1))) void*)g,
        (__attribute__((address_space(3))) void*)l, 16, 0, 0);
}

// ---------------------------------------------------------------------------
// K0a: weights f32 -> bf16, pre-swizzled [half2][kb16][row256][slot4*16B].
// half 0 = w1p rows, half 1 = w1g rows. Dest slot s holds source chunk
// sc = s ^ ((row>>1)&3). One 16B chunk per thread; grid 128 x 256.
// ---------------------------------------------------------------------------
__global__ __launch_bounds__(256) void k0_weights(
    const float* __restrict__ w1p, const float* __restrict__ w1g,
    short* __restrict__ wT)
{
    int g = blockIdx.x * 256 + threadIdx.x;   // 0..32767 chunk id
    int half = g >> 14;
    int kb   = (g >> 10) & 15;
    int row  = (g >> 2) & 255;
    int s    = g & 3;
    int sc   = s ^ ((row >> 1) & 3);
    const float* src = (half == 0) ? (w1p + (size_t)row * CIN)
                                   : (w1g + (size_t)row * CIN);
    int c = kb * 32 + sc * 8;
    float f[8];
    *(float4*)(f)     = *(const float4*)(src + c);
    *(float4*)(f + 4) = *(const float4*)(src + c + 4);
    bf16x8 v;
    #pragma unroll
    for (int i = 0; i < 8; ++i) v[i] = f2bf(f[i]);
    *(bf16x8*)((char*)wT + (size_t)half * 262144 + kb * 16384 + row * 64 + s * 16) = v;
}

// ---------------------------------------------------------------------------
// K1: fused transpose + conv1p/conv1g bf16 MFMA GEMM.
// Block = one half (p or g): M=256 x N=128(hw), BK=32, 512 thr (8 waves 4x2,
// per-wave 64x64). A: global_load_lds from pre-swizzled wT, 3 bufs.
// B: reg-staged from x (8 f32/thread, coalesced over hw) -> cvt -> CONFLICT-
// FREE swizzled ds_write_b128 (dest slot = bs ^ ((brow>>1)&3)), 3 bufs.
// Phase shape: {8 ds_read frags; ALOAD(t+2); MFMA x16; vmcnt(2); BWRITE(t+1);
// BLOAD(t+2); lgkmcnt(0); barrier} -- the staging wait sits AFTER the MFMA
// cluster so B-load latency hides under compute. vmcnt never 0 mid-loop.
// LDS 72KB -> 2 blocks/CU. Grid 1536, XCD-bijective, half fastest.
// ---------------------------------------------------------------------------
__global__ __launch_bounds__(512, 4) void k1_conv1(
    const float* __restrict__ x, const short* __restrict__ wT,
    const float* __restrict__ mask, const float* __restrict__ beta_g,
    short* __restrict__ outp_pre, float* __restrict__ psum, float* __restrict__ pmax)
{
    int orig = blockIdx.x;
    int newid = (orig & 7) * 192 + (orig >> 3);   // 1536 = 8*192, bijective
    int half = newid & 1;
    int nb = newid >> 1;          // b*3 + n
    int n = nb % 3;
    int b = nb / 3;

    const int tid = threadIdx.x;
    const int lane = tid & 63, wid = tid >> 6;
    const int wm = wid >> 1, wn = wid & 1;        // 4 x 2 waves, 64x64 each
    const int lc = lane & 15, lg = lane >> 4;
    const int hw0 = n * 128;

    __shared__ __align__(16) short As[3][8192];   // 3 x 16KB [row256][64B]
    __shared__ __align__(16) short Bs[3][4096];   // 3 x  8KB [row128][64B]
    __shared__ float maskS[128], betaS[256];
    float* redS = (float*)(&As[0][0]);            // epilogue overlay (4KB)
    float* redM = redS + 512;

    if (tid < 128) {
        int hwg_ = hw0 + tid;
        maskS[tid] = (hwg_ < HW) ? mask[b * HW + hwg_] : 0.f;
    }
    if (tid < 256) betaS[tid] = beta_g[tid];
    asm volatile("s_waitcnt vmcnt(0) lgkmcnt(0)" ::: "memory");
    __builtin_amdgcn_sched_barrier(0);

    // ---- B (x) staging geometry: thread loads source chunk bs (constant),
    // writes to physical slot bs ^ ((brow>>1)&3) -> conflict-free banks.
    const int brow = tid & 127;            // hw within tile
    const int bs   = tid >> 7;             // source chunk 0..3
    const int hwg  = hw0 + brow;
    const bool bvalid = hwg < HW;
    const float* xb = x + ((size_t)b * CIN + bs * 8) * HW + hwg;
    const int bDstOff = brow * 64 + ((bs ^ ((brow >> 1) & 3)) * 16);
    char* bDstBase = (char*)Bs;

    // ---- A staging: 2 chunks/thread from wT
    const char* aSrc = (const char*)wT + (size_t)half * 262144 + tid * 16;
    char* aDst = (char*)As + tid * 16;

    // per-thread invariant fragment byte-offsets
    int aOff[4], bOff[4];
    #pragma unroll
    for (int mf = 0; mf < 4; ++mf) {
        int r = wm * 64 + mf * 16 + lc;            // 0..255
        aOff[mf] = r * 64 + ((lg ^ ((r >> 1) & 3)) * 16);
    }
    #pragma unroll
    for (int nf = 0; nf < 4; ++nf) {
        int r = wn * 64 + nf * 16 + lc;            // 0..127
        bOff[nf] = r * 64 + ((lg ^ ((r >> 1) & 3)) * 16);
    }

    float regB[8];
    #pragma unroll
    for (int i = 0; i < 8; ++i) regB[i] = 0.f;

    f32x4 acc[4][4];
    #pragma unroll
    for (int i = 0; i < 4; ++i)
        #pragma unroll
        for (int j = 0; j < 4; ++j)
            acc[i][j] = (f32x4){0.f, 0.f, 0.f, 0.f};

#define BLOAD(kb)                                                          \
    do {                                                                   \
        const float* src_ = xb + (size_t)(kb) * 32 * HW;                   \
        _Pragma("unroll")                                                  \
        for (int i_ = 0; i_ < 8; ++i_) {                                   \
            regB[i_] = bvalid ? src_[(size_t)i_ * HW] : 0.f;               \
        }                                                                  \
    } while (0)

#define BWRITE(buf)                                                        \
    do {                                                                   \
        bf16x8 o_;                                                         \
        _Pragma("unroll")                                                  \
        for (int i_ = 0; i_ < 8; ++i_) o_[i_] = f2bf(regB[i_]);            \
        *(bf16x8*)(bDstBase + (buf) * 8192 + bDstOff) = o_;                \
    } while (0)

#define ALOAD(buf, kb)                                                     \
    do {                                                                   \
        gl_lds16(aSrc + (kb) * 16384,        aDst + (buf) * 16384);        \
        gl_lds16(aSrc + (kb) * 16384 + 8192, aDst + (buf) * 16384 + 8192); \
    } while (0)

    // ---- prologue: queue discipline -> at phase t entry: [A(t+1)2, B(t+1)8]
    ALOAD(0, 0); BLOAD(0);                       // queue: A0(2) B0(8)
    ALOAD(1, 1);                                 // +A1(2) = 12
    asm volatile("s_waitcnt vmcnt(2)" ::: "memory");   // A0,B0 done; A1 flying
    __builtin_amdgcn_sched_barrier(0);
    BWRITE(0);
    BLOAD(1);                                    // queue: A1(2) B1(8)
    asm volatile("s_waitcnt lgkmcnt(0)" ::: "memory");
    __builtin_amdgcn_s_barrier();
    __builtin_amdgcn_sched_barrier(0);

    #pragma unroll
    for (int t = 0; t < 16; ++t) {
        const int buf = t % 3;
        const char* ab = (const char*)As + buf * 16384;
        const char* bb = (const char*)Bs + buf * 8192;

        // frag reads for THIS phase (compiler interleaves lgkm with MFMA)
        bf16x8 aF[4], bF[4];
        #pragma unroll
        for (int mf = 0; mf < 4; ++mf) aF[mf] = *(const bf16x8*)(ab + aOff[mf]);
        #pragma unroll
        for (int nf = 0; nf < 4; ++nf) bF[nf] = *(const bf16x8*)(bb + bOff[nf]);

        // A-stage for t+2: fire-and-forget into buffer (t+2)%3
        if (t < 14) { ALOAD((t + 2) % 3, t + 2); }   // queue: +A(t+2)2 = 12

        __builtin_amdgcn_s_setprio(1);
        #pragma unroll
        for (int mf = 0; mf < 4; ++mf)
            #pragma unroll
            for (int nf = 0; nf < 4; ++nf)
                acc[mf][nf] = __builtin_amdgcn_mfma_f32_16x16x32_bf16(
                    aF[mf], bF[nf], acc[mf][nf], 0, 0, 0);
        __builtin_amdgcn_s_setprio(0);

        // staging group AFTER compute: wait hides under the MFMA cluster
        if (t < 14) {
            asm volatile("s_waitcnt vmcnt(2)" ::: "memory");  // A(t+1),B(t+1) done
            __builtin_amdgcn_sched_barrier(0);
            BWRITE((t + 1) % 3);
            BLOAD(t + 2);                          // queue: A(t+2)2 B(t+2)8
        } else if (t == 14) {
            asm volatile("s_waitcnt vmcnt(0)" ::: "memory");  // A15,B15 done
            __builtin_amdgcn_sched_barrier(0);
            BWRITE(15 % 3);
        }
        if (t < 15) {
            asm volatile("s_waitcnt lgkmcnt(0)" ::: "memory");
            __builtin_amdgcn_s_barrier();
            __builtin_amdgcn_sched_barrier(0);
        }
    }
    __syncthreads();   // LDS reads done; As reused as redS/redM

    if (half == 0) {
        // p-half: store pre-activation conv1p output (bf16), rows 0..255
        #pragma unroll
        for (int mf = 0; mf < 4; ++mf) {
            int ch = wm * 64 + mf * 16 + lg * 4;
            #pragma unroll
            for (int nf = 0; nf < 4; ++nf) {
                int hw = hw0 + wn * 64 + nf * 16 + lc;
                if (hw < HW) {
                    #pragma unroll
                    for (int j = 0; j < 4; ++j)
                        outp_pre[((size_t)(b * CP + ch + j)) * HW + hw] = f2bf(acc[mf][nf][j]);
                }
            }
        }
    } else {
        // g-half: mish((acc+beta)*mask); per-channel sum & max partials
        #pragma unroll
        for (int mf = 0; mf < 4; ++mf) {
            #pragma unroll
            for (int j = 0; j < 4; ++j) {
                int rloc = wm * 64 + mf * 16 + lg * 4 + j;   // 0..255
                float beta = betaS[rloc];
                float s = 0.f, mx = -INFINITY;
                #pragma unroll
                for (int nf = 0; nf < 4; ++nf) {
                    int cl = wn * 64 + nf * 16 + lc;
                    int hw = hw0 + cl;
                    float mv = maskS[cl];
                    float val = mish_f((acc[mf][nf][j] + beta) * mv);
                    if (hw < HW) {
                        s += val * mv;
                        mx = fmaxf(mx, val + mv - 1.f);
                    }
                }
                #pragma unroll
                for (int off = 1; off < 16; off <<= 1) {
                    s += __shfl_xor(s, off, 64);
                    mx = fmaxf(mx, __shfl_xor(mx, off, 64));
                }
                if (lc == 0) { redS[rloc * 2 + wn] = s; redM[rloc * 2 + wn] = mx; }
            }
        }
        __syncthreads();
        if (tid < 256) {
            float s = redS[tid * 2] + redS[tid * 2 + 1];
            float mx = fmaxf(redM[tid * 2], redM[tid * 2 + 1]);
            psum[((size_t)(b * CP + tid)) * 3 + n] = s;
            pmax[((size_t)(b * CP + tid)) * 3 + n] = mx;
        }
    }
#undef BLOAD
#undef BWRITE
#undef ALOAD
}

// ---------------------------------------------------------------------------
// K2: per-batch pooled vector + linear_g. Grid 256 blocks x 256 threads.
// ---------------------------------------------------------------------------
__global__ __launch_bounds__(256) void k2_pool_linear(
    const float* __restrict__ mask, const float* __restrict__ psum,
    const float* __restrict__ pmax, const float* __restrict__ lw,
    float* __restrict__ g_out)
{
    int b = blockIdx.x, t = threadIdx.x;
    __shared__ float pooled[768];
    __shared__ float msr[4];

    float s = 0.f;
    for (int i = t; i < HW; i += 256) s += mask[b * HW + i];
    #pragma unroll
    for (int off = 1; off < 64; off <<= 1) s += __shfl_xor(s, off, 64);
    if ((t & 63) == 0) msr[t >> 6] = s;
    __syncthreads();
    float msum = msr[0] + msr[1] + msr[2] + msr[3];

    {
        int c = t;
        const float* ps = psum + (size_t)(b * CP + c) * 3;
        const float* pm = pmax + (size_t)(b * CP + c) * 3;
        float s3 = ps[0] + ps[1] + ps[2];
        float m3 = fmaxf(fmaxf(pm[0], pm[1]), pm[2]);
        float mean = s3 / msum;
        float sq = (sqrtf(msum) - 14.f) * 0.1f;
        pooled[c] = mean; pooled[256 + c] = mean * sq; pooled[512 + c] = m3;
    }
    __syncthreads();
    {
        int o = t;
        const float4* wrow = (const float4*)(lw + (size_t)o * 768);
        float acc = 0.f;
        #pragma unroll 8
        for (int j = 0; j < 192; ++j) {
            float4 w4 = wrow[j];
            float4 p4 = *(const float4*)&pooled[j * 4];
            acc += p4.x * w4.x + p4.y * w4.y + p4.z * w4.z + p4.w * w4.w;
        }
        g_out[b * CP + o] = acc;
    }
}

// ---------------------------------------------------------------------------
// K3: final fused mish((outp_pre+g+beta2)*mask) -> conv2p -> mask bias.
// outp_pre is bf16. Grid (6 hw-tiles, 256 b) x 256 threads.
// ---------------------------------------------------------------------------
__global__ __launch_bounds__(256) void k3_final(
    const short* __restrict__ outp_pre, const float* __restrict__ mask,
    const float* __restrict__ g_out, const float* __restrict__ beta2,
    const float* __restrict__ w2, float* __restrict__ out)
{
    int ht = blockIdx.x, b = blockIdx.y;
    int t = threadIdx.x;
    __shared__ float w2S[NOUT * 256];
    __shared__ float gbS[256];
    __shared__ float part[NOUT][256];

    for (int i = t; i < NOUT * 256; i += 256) w2S[i] = w2[i];
    gbS[t] = g_out[b * CP + t] + beta2[t];
    __syncthreads();

    int hw = t & 63, cg = t >> 6;
    int hwg = ht * 64 + hw;
    bool valid = hwg < HW;
    float maskv = valid ? mask[b * HW + hwg] : 0.f;

    float acc[NOUT] = {0.f, 0.f, 0.f, 0.f, 0.f, 0.f};
    const short* src = outp_pre + ((size_t)(b * CP + cg * 64)) * HW + hwg;
    #pragma unroll 4
    for (int ci = 0; ci < 64; ++ci) {
        float v = valid ? bf2f(src[(size_t)ci * HW]) : 0.f;
        float mm = mish_f((v + gbS[cg * 64 + ci]) * maskv);
        #pragma unroll
        for (int o = 0; o < NOUT; ++o) acc[o] += mm * w2S[o * 256 + cg * 64 + ci];
    }
    #pragma unroll
    for (int o = 0; o < NOUT; ++o) part[o][t] = acc[o];
    __syncthreads();

    for (int idx = t; idx < NOUT * 64; idx += 256) {
        int o = idx >> 6, h2 = idx & 63;
        int hg = ht * 64 + h2;
        if (hg < HW) {
            float mv = mask[b * HW + hg];
            float sum = part[o][h2] + part[o][64 + h2] + part[o][128 + h2] + part[o][192 + h2];
            out[((size_t)(b * NOUT + o)) * HW + hg] = sum - (1.f - mv) * 5000.f;
        }
    }
}

extern "C" void kernel_launch(void* const* d_in, const int* in_sizes, int n_in,
                              void* d_out, int out_size, void* d_ws, size_t ws_size,
                              hipStream_t stream) {
    const float* x     = (const float*)d_in[0];
    const float* mask  = (const float*)d_in[1];
    const float* w1p   = (const float*)d_in[2];
    const float* w1g   = (const float*)d_in[3];
    const float* betag = (const float*)d_in[4];
    const float* lw    = (const float*)d_in[5];
    const float* beta2 = (const float*)d_in[6];
    const float* w2    = (const float*)d_in[7];
    float* out = (float*)d_out;

    char* ws = (char*)d_ws;
    short* outp_pre = (short*)(ws);                      // 256*256*361*2 = 47,316,992 B
    short* wT       = (short*)(ws + 47316992);           // 2*262144      =     524,288 B
    float* psum     = (float*)(ws + 47841280);           // 256*256*3*4   =     786,432 B
    float* pmax     = (float*)(ws + 48627712);           // 256*256*3*4   =     786,432 B
    float* g_out    = (float*)(ws + 49414144);           // 256*256*4     =     262,144 B

    hipLaunchKernelGGL(k0_weights, dim3(128), dim3(256), 0, stream, w1p, w1g, wT);
    hipLaunchKernelGGL(k1_conv1, dim3(1536), dim3(512), 0, stream,
                       x, wT, mask, betag, outp_pre, psum, pmax);
    hipLaunchKernelGGL(k2_pool_linear, dim3(BATCH), dim3(256), 0, stream,
                       mask, psum, pmax, lw, g_out);
    hipLaunchKernelGGL(k3_final, dim3(6, BATCH), dim3(256), 0, stream,
                       outp_pre, mask, g_out, beta2, w2, out);
    (void)in_sizes; (void)n_in; (void)out_size; (void)ws_size;
}